// Round 11
// baseline (377.308 us; speedup 1.0000x reference)
//
#include <hip/hip_runtime.h>
#include <math.h>

// Dims: L=2048 N=4 E=1024 H=16 D=128 HD=64; 2D=256; M=L*N=8192; B=64
// phi natural (l,n,h,d) flat order == reference's scrambled (b,l',d) view.
// attn row mapping: flat l*4096 + b*64 + hd == (l*4+nb)*1024 + (h16*64+hd), b=nb*16+h16.
// Chunked causal: CHK=256, NC=8.

typedef unsigned short u16;
typedef unsigned int u32;
using f32x4v  = __attribute__((ext_vector_type(4))) float;
using f32x16v = __attribute__((ext_vector_type(16))) float;
using s16x8   = __attribute__((ext_vector_type(8))) short;

__device__ __forceinline__ float bf2f(u16 u) { return __uint_as_float(((u32)u) << 16); }
__device__ __forceinline__ u16 f2bf(float x) {
    u32 b = __float_as_uint(x);
    b += 0x7fff + ((b >> 16) & 1);          // RNE
    return (u16)(b >> 16);
}
__device__ __forceinline__ u32 cvtpk(float lo, float hi) {
    u32 r;
    asm("v_cvt_pk_bf16_f32 %0, %1, %2" : "=v"(r) : "v"(lo), "v"(hi));
    return r;
}
__device__ __forceinline__ float exp2f_hw(float x) {
    float r;
    asm("v_exp_f32 %0, %1" : "=v"(r) : "v"(x));
    return r;
}
__device__ __forceinline__ void gload_lds16(const void* g, void* l) {
    __builtin_amdgcn_global_load_lds(
        (const __attribute__((address_space(1))) void*)g,
        (__attribute__((address_space(3))) void*)l, 16, 0, 0);
}

// ---------------------------------------------------------------------------
// Weights + rm -> bf16 (one launch)
__global__ __launch_bounds__(256) void cvt_consts(
    const float* __restrict__ w0, const float* __restrict__ w1,
    const float* __restrict__ w2, const float* __restrict__ w3,
    const float* __restrict__ rm, u16* __restrict__ wbf, u16* __restrict__ rmb)
{
    const int y = blockIdx.y;
    const float* src;
    u16* d;
    if (y == 4) {
        if (blockIdx.x >= 64) return;
        src = rm; d = rmb;
    } else {
        src = (y == 0) ? w0 : (y == 1) ? w1 : (y == 2) ? w2 : w3;
        d = wbf + (size_t)y * 1048576;
    }
    const size_t i = ((size_t)blockIdx.x * 256 + threadIdx.x) * 8;
    const float4 a = *(const float4*)(src + i);
    const float4 b = *(const float4*)(src + i + 4);
    u16 o[8] = {f2bf(a.x), f2bf(a.y), f2bf(a.z), f2bf(a.w),
                f2bf(b.x), f2bf(b.y), f2bf(b.z), f2bf(b.w)};
    *(uint4*)(d + i) = *(uint4*)o;
}

// ---------------------------------------------------------------------------
// QKV projection GEMM, one dispatch (z selects). A = f32 input, reg-staged +
// converted (identical rounding to the old cvt_x path); B = bf16 weights via
// global_load_lds. C[m][n] = sum_k A[m][k]*B[n][k] + bias[n].
// z<2 -> bf16 row-major (qp/kp); z==2 -> vpt[(b*64+hd)*2048 + k].
__global__ __launch_bounds__(256) void gemm_qkv(
    const float* __restrict__ Xq, const float* __restrict__ Xk, const float* __restrict__ Xv,
    const u16* __restrict__ WB, const float* __restrict__ bq, const float* __restrict__ bk,
    const float* __restrict__ bv, u16* __restrict__ qp, u16* __restrict__ kp, u16* __restrict__ vpt)
{
    __shared__ __align__(16) u16 As[4096];   // [128][32], 16B-slot XOR swizzle
    __shared__ __align__(16) u16 Bs[4096];   // [128][32] linear (gload_lds)
    const int z = blockIdx.z;
    const float* A = (z == 0) ? Xq : (z == 1) ? Xk : Xv;
    const u16* Bw = WB + (size_t)z * 1048576;
    const float* bias = (z == 0) ? bq : (z == 1) ? bk : bv;

    const int t = threadIdx.x;
    const int m0 = blockIdx.x * 128, n0 = blockIdx.y * 128;
    const int wid = t >> 6, lane = t & 63;
    const int wr = wid >> 1, wc = wid & 1;
    const int l15 = lane & 15, l4 = lane >> 4;

    f32x4v acc[4][4];
#pragma unroll
    for (int i = 0; i < 4; ++i)
#pragma unroll
        for (int j = 0; j < 4; ++j)
#pragma unroll
            for (int e = 0; e < 4; ++e) acc[i][j][e] = 0.f;

    // A staging map (round-2 verified): 2 threads/row, 16 f32 each
    const int srow = t >> 1;
    const int scol = (t & 1) * 16;
    const int sx   = (srow >> 1) & 3;
    const int sl0  = (t & 1) * 2;
    u16* wa0 = &As[srow * 32 + ((sl0     ^ sx)) * 8];
    u16* wa1 = &As[srow * 32 + (((sl0+1) ^ sx)) * 8];
    const float* gsrcA = A + (size_t)(m0 + srow) * 1024 + scol;
    // B staging (gload_lds linear)
    const int brow = wid * 32 + (lane >> 2);
    const int bcol = (lane & 3) * 8;
    const u16* gb0 = Bw + (size_t)(n0 + brow) * 1024 + bcol;
    const u16* gb1 = gb0 + 16 * 1024;
    u16* lb0 = &Bs[wid * 1024];
    u16* lb1 = lb0 + 512;

    for (int k0 = 0; k0 < 1024; k0 += 32) {
        __syncthreads();
        gload_lds16(gb0 + k0, lb0);
        gload_lds16(gb1 + k0, lb1);
        {
            u16 ta[16];
#pragma unroll
            for (int q = 0; q < 4; ++q) {
                const float4 v = *(const float4*)(gsrcA + k0 + q * 4);
                ta[q*4+0] = f2bf(v.x); ta[q*4+1] = f2bf(v.y);
                ta[q*4+2] = f2bf(v.z); ta[q*4+3] = f2bf(v.w);
            }
            *(uint4*)wa0 = *(const uint4*)&ta[0];
            *(uint4*)wa1 = *(const uint4*)&ta[8];
        }
        __syncthreads();
        s16x8 af[4], bfr[4];
#pragma unroll
        for (int fi = 0; fi < 4; ++fi) {
            const int r  = wr * 64 + fi * 16 + l15;
            const int sl = l4 ^ ((r >> 1) & 3);
            af[fi] = *(const s16x8*)&As[r * 32 + sl * 8];
        }
#pragma unroll
        for (int fj = 0; fj < 4; ++fj)
            bfr[fj] = *(const s16x8*)&Bs[(wc * 64 + fj * 16 + l15) * 32 + l4 * 8];
#pragma unroll
        for (int fi = 0; fi < 4; ++fi)
#pragma unroll
            for (int fj = 0; fj < 4; ++fj)
                acc[fi][fj] = __builtin_amdgcn_mfma_f32_16x16x32_bf16(af[fi], bfr[fj], acc[fi][fj], 0, 0, 0);
    }

    u16* Cp = (z == 0) ? qp : (z == 1) ? kp : vpt;
    const int rl = l4 * 4, cl = l15;
    float bvals[4];
#pragma unroll
    for (int fj = 0; fj < 4; ++fj) bvals[fj] = bias[n0 + wc * 64 + fj * 16 + cl];
#pragma unroll
    for (int fi = 0; fi < 4; ++fi)
#pragma unroll
        for (int j = 0; j < 4; ++j) {
            const size_t m = m0 + wr * 64 + fi * 16 + rl + j;
#pragma unroll
            for (int fj = 0; fj < 4; ++fj) {
                const int n = n0 + wc * 64 + fj * 16 + cl;
                const float v = acc[fi][fj][j] + bvals[fj];
                if (z < 2) Cp[m * 1024 + n] = f2bf(v);
                else       Cp[((size_t)((m & 3) * 16 + (n >> 6)) * 64 + (n & 63)) * 2048 + (m >> 2)] = f2bf(v);
            }
        }
}

// ---------------------------------------------------------------------------
// Output GEMM: A bf16 (gload_lds), B bf16 weights (gload_lds), f32 out.
__global__ __launch_bounds__(256) void gemm_o(
    const u16* __restrict__ A, const u16* __restrict__ Bw,
    const float* __restrict__ bias, float* __restrict__ Cp)
{
    __shared__ __align__(16) u16 As[4096];
    __shared__ __align__(16) u16 Bs[4096];
    const int t = threadIdx.x;
    const int m0 = blockIdx.x * 128, n0 = blockIdx.y * 128;
    const int wid = t >> 6, lane = t & 63;
    const int wr = wid >> 1, wc = wid & 1;
    const int l15 = lane & 15, l4 = lane >> 4;

    f32x4v acc[4][4];
#pragma unroll
    for (int i = 0; i < 4; ++i)
#pragma unroll
        for (int j = 0; j < 4; ++j)
#pragma unroll
            for (int e = 0; e < 4; ++e) acc[i][j][e] = 0.f;

    const int srow = wid * 32 + (lane >> 2);
    const int scol = (lane & 3) * 8;
    const u16* ga0 = A  + (size_t)(m0 + srow) * 1024 + scol;
    const u16* ga1 = ga0 + 16 * 1024;
    const u16* gb0 = Bw + (size_t)(n0 + srow) * 1024 + scol;
    const u16* gb1 = gb0 + 16 * 1024;
    u16* la0 = &As[wid * 1024];
    u16* la1 = la0 + 512;
    u16* lb0 = &Bs[wid * 1024];
    u16* lb1 = lb0 + 512;

    for (int k0 = 0; k0 < 1024; k0 += 32) {
        __syncthreads();
        gload_lds16(ga0 + k0, la0);
        gload_lds16(ga1 + k0, la1);
        gload_lds16(gb0 + k0, lb0);
        gload_lds16(gb1 + k0, lb1);
        __syncthreads();
        s16x8 af[4], bfr[4];
#pragma unroll
        for (int fi = 0; fi < 4; ++fi)
            af[fi] = *(const s16x8*)&As[(wr * 64 + fi * 16 + l15) * 32 + l4 * 8];
#pragma unroll
        for (int fj = 0; fj < 4; ++fj)
            bfr[fj] = *(const s16x8*)&Bs[(wc * 64 + fj * 16 + l15) * 32 + l4 * 8];
#pragma unroll
        for (int fi = 0; fi < 4; ++fi)
#pragma unroll
            for (int fj = 0; fj < 4; ++fj)
                acc[fi][fj] = __builtin_amdgcn_mfma_f32_16x16x32_bf16(af[fi], bfr[fj], acc[fi][fj], 0, 0, 0);
    }

    const int rl = l4 * 4, cl = l15;
    float bvals[4];
#pragma unroll
    for (int fj = 0; fj < 4; ++fj) bvals[fj] = bias[n0 + wc * 64 + fj * 16 + cl];
#pragma unroll
    for (int fi = 0; fi < 4; ++fi)
#pragma unroll
        for (int j = 0; j < 4; ++j) {
            const size_t m = m0 + wr * 64 + fi * 16 + rl + j;
#pragma unroll
            for (int fj = 0; fj < 4; ++fj) {
                const int n = n0 + wc * 64 + fj * 16 + cl;
                Cp[m * 1024 + n] = acc[fi][fj][j] + bvals[fj];
            }
        }
}

// ---------------------------------------------------------------------------
// Random projection via MFMA (unchanged from round 10).
__global__ __launch_bounds__(256) void rand_project_mfma(
    const u16* __restrict__ QP, const u16* __restrict__ KP,
    const u16* __restrict__ RMB, u16* __restrict__ PHIQ, u16* __restrict__ PHIK)
{
    const u16* X  = (blockIdx.z == 0) ? QP : KP;
    u16* PHI      = (blockIdx.z == 0) ? PHIQ : PHIK;
    __shared__ __align__(16) u16 Xs[128 * 72];
    __shared__ __align__(16) u16 RMs[128 * 72];
    __shared__ float rsl_lds[128];
    const int h  = blockIdx.x;
    const int r0 = blockIdx.y * 128;
    const int t  = threadIdx.x;
    const int w  = t >> 6, lane = t & 63;
    const int l15 = lane & 15, l4 = lane >> 4;

    float sq[4];
#pragma unroll
    for (int i = 0; i < 4; ++i) {
        const int lin = t + i * 256;
        const int row = lin >> 3, oct = lin & 7;
        const uint4 xv = *(const uint4*)(X + (size_t)(r0 + row) * 1024 + h * 64 + oct * 8);
        *(uint4*)&Xs[row * 72 + oct * 8] = xv;
        const u16* pv = (const u16*)&xv;
        float s = 0.f;
#pragma unroll
        for (int e = 0; e < 8; ++e) { const float f = bf2f(pv[e]); s += f * f; }
        sq[i] = s;
        const uint4 rv = *(const uint4*)(RMB + (size_t)h * 8192 + lin * 8);
        *(uint4*)&RMs[row * 72 + oct * 8] = rv;
    }
#pragma unroll
    for (int i = 0; i < 4; ++i) {
        sq[i] += __shfl_xor(sq[i], 1);
        sq[i] += __shfl_xor(sq[i], 2);
        sq[i] += __shfl_xor(sq[i], 4);
        if ((t & 7) == 0)
            rsl_lds[(t >> 3) + i * 32] = 1.4426950408889634f / fmaxf(sqrtf(sq[i]), 1e-12f);
    }
    __syncthreads();

    const int wr = (w >> 1) * 64, wc = (w & 1) * 64;
    f32x4v acc[4][4];
#pragma unroll
    for (int i = 0; i < 4; ++i)
#pragma unroll
        for (int j = 0; j < 4; ++j)
#pragma unroll
            for (int e = 0; e < 4; ++e) acc[i][j][e] = 0.f;
#pragma unroll
    for (int ks = 0; ks < 2; ++ks) {
        s16x8 af[4], bfr[4];
#pragma unroll
        for (int fi = 0; fi < 4; ++fi)
            af[fi] = *(const s16x8*)&Xs[(wr + fi * 16 + l15) * 72 + ks * 32 + l4 * 8];
#pragma unroll
        for (int fj = 0; fj < 4; ++fj)
            bfr[fj] = *(const s16x8*)&RMs[(wc + fj * 16 + l15) * 72 + ks * 32 + l4 * 8];
#pragma unroll
        for (int fi = 0; fi < 4; ++fi)
#pragma unroll
            for (int fj = 0; fj < 4; ++fj)
                acc[fi][fj] = __builtin_amdgcn_mfma_f32_16x16x32_bf16(af[fi], bfr[fj], acc[fi][fj], 0, 0, 0);
    }

#pragma unroll
    for (int fi = 0; fi < 4; ++fi)
#pragma unroll
        for (int reg = 0; reg < 4; ++reg) {
            const int row = wr + fi * 16 + l4 * 4 + reg;
            const float rsl = rsl_lds[row];
            const size_t base = ((size_t)(r0 + row) * 16 + h) * 256;
#pragma unroll
            for (int fj = 0; fj < 4; ++fj) {
                const int d = wc + fj * 16 + l15;
                const float arg = acc[fi][fj][reg] * rsl;
                PHI[base + d]       = f2bf(exp2f_hw(arg - 4.f));
                PHI[base + 128 + d] = f2bf(exp2f_hw(-arg - 4.f));
            }
        }
}

// ---------------------------------------------------------------------------
// Chunk state via MFMA -> bf16 chunk sums (stc).
__global__ __launch_bounds__(256) void chunk_state_mfma(
    const u16* __restrict__ PHIK, const u16* __restrict__ VPT, u16* __restrict__ STC)
{
    __shared__ __align__(16) u16 Ks[64 * 136];
    __shared__ float zlds[16][132];
    const int b = blockIdx.x;
    const int c = blockIdx.y >> 1;
    const int dh = blockIdx.y & 1;
    const int t = threadIdx.x;
    const int wid = t >> 6, lane = t & 63;
    const int l15 = lane & 15, l4 = lane >> 4;
    const int wr = wid >> 1, wc = wid & 1;

    const size_t R0 = (size_t)b * 2048 + (size_t)c * 256;
    const int rgrp = t >> 4, d08 = (t & 15) * 8;

    float zpart[8];
#pragma unroll
    for (int i = 0; i < 8; ++i) zpart[i] = 0.f;

    f32x4v acc[2][4];
#pragma unroll
    for (int i = 0; i < 2; ++i)
#pragma unroll
        for (int j = 0; j < 4; ++j)
#pragma unroll
            for (int e = 0; e < 4; ++e) acc[i][j][e] = 0.f;

    for (int stage = 0; stage < 4; ++stage) {
        __syncthreads();
#pragma unroll
        for (int j = 0; j < 4; ++j) {
            const int r = rgrp + 16 * j;
            const uint4 v = *(const uint4*)(PHIK + (R0 + stage * 64 + r) * 256 + dh * 128 + d08);
            const int x = ((r >> 3) & 3) << 1;
            *(uint4*)&Ks[r * 136 + (((d08 >> 3) ^ x) << 3)] = v;
            const u16* pv = (const u16*)&v;
#pragma unroll
            for (int i = 0; i < 8; ++i) zpart[i] += bf2f(pv[i]);
        }
        __syncthreads();
#pragma unroll
        for (int ks = 0; ks < 2; ++ks) {
            const int xk = ((ks * 4 + l4) & 3) << 1;
            const int r0 = ks * 32 + l4 * 8;
            s16x8 af[2], bk[4];
#pragma unroll
            for (int fi = 0; fi < 2; ++fi) {
                const int h = wr * 32 + fi * 16 + l15;
                af[fi] = *(const s16x8*)(VPT + ((size_t)b * 64 + h) * 2048 + c * 256 + stage * 64 + ks * 32 + l4 * 8);
            }
#pragma unroll
            for (int fj = 0; fj < 4; ++fj) {
                const int d = wc * 64 + fj * 16 + l15;
                const int colk = (((d >> 3) ^ xk) << 3) + (d & 7);
#pragma unroll
                for (int e = 0; e < 8; ++e)
                    bk[fj][e] = (short)Ks[(r0 + e) * 136 + colk];
            }
#pragma unroll
            for (int fi = 0; fi < 2; ++fi)
#pragma unroll
                for (int fj = 0; fj < 4; ++fj)
                    acc[fi][fj] = __builtin_amdgcn_mfma_f32_16x16x32_bf16(af[fi], bk[fj], acc[fi][fj], 0, 0, 0);
        }
    }
    __syncthreads();
    *(float4*)&zlds[rgrp][d08]     = *(float4*)&zpart[0];
    *(float4*)&zlds[rgrp][d08 + 4] = *(float4*)&zpart[4];
    __syncthreads();
    u16* st = STC + (size_t)(b * 8 + c) * 16640;
    if (t < 128) {
        float z = 0.f;
#pragma unroll
        for (int g = 0; g < 16; ++g) z += zlds[g][t];
        st[16384 + dh * 128 + t] = f2bf(z);
    }
#pragma unroll
    for (int fi = 0; fi < 2; ++fi)
#pragma unroll
        for (int reg = 0; reg < 4; ++reg) {
            const int h = wr * 32 + fi * 16 + l4 * 4 + reg;
#pragma unroll
            for (int fj = 0; fj < 4; ++fj) {
                const int d = dh * 128 + wc * 64 + fj * 16 + l15;
                st[(size_t)h * 256 + d] = f2bf(acc[fi][fj][reg]);
            }
        }
}

// ---------------------------------------------------------------------------
// Exclusive prefix over 8 chunks (f32 accumulation of bf16 chunk sums).
__global__ void prefix_scan(const u16* __restrict__ STC, u16* __restrict__ STBF)
{
    const int b = blockIdx.x;
    const int e = blockIdx.y * 256 + threadIdx.x;
    if (e >= 16640) return;
    float run = 0.f;
#pragma unroll
    for (int c = 0; c < 8; ++c) {
        const size_t idx = (size_t)(b * 8 + c) * 16640 + e;
        const float v = bf2f(STC[idx]);
        STBF[idx] = f2bf(run);
        run += v;
    }
}

// ---------------------------------------------------------------------------
// Intra-chunk unit with compile-time trip count (enables unroll + load hoisting).
template<int KBMAX>
__device__ __forceinline__ void intra_unit(
    const u16* __restrict__ kbase, const u16* __restrict__ vbase,
    const s16x8 (&qf)[16], int qc, int l31, int s,
    f32x16v& o0, f32x16v& o1, float& den)
{
#pragma unroll
    for (int kb = 0; kb <= KBMAX; ++kb) {
        s16x8 vf[2][2];
#pragma unroll
        for (int kh = 0; kh < 2; ++kh)
#pragma unroll
            for (int fh = 0; fh < 2; ++fh)
                vf[kh][fh] = *(const s16x8*)(vbase + (size_t)(fh * 32 + l31) * 2048
                                             + kb * 32 + kh * 16 + s * 8);
        f32x16v p0, p1;
#pragma unroll
        for (int e = 0; e < 16; ++e) { p0[e] = 0.f; p1[e] = 0.f; }
        const u16* kptr = kbase + (size_t)(kb * 32 + l31) * 256 + s * 8;
        __builtin_amdgcn_s_setprio(1);
#pragma unroll
        for (int ds = 0; ds < 8; ++ds) {
            const s16x8 kf0 = *(const s16x8*)(kptr + (2 * ds) * 16);
            const s16x8 kf1 = *(const s16x8*)(kptr + (2 * ds + 1) * 16);
            p0 = __builtin_amdgcn_mfma_f32_32x32x16_bf16(kf0, qf[2 * ds],     p0, 0, 0, 0);
            p1 = __builtin_amdgcn_mfma_f32_32x32x16_bf16(kf1, qf[2 * ds + 1], p1, 0, 0, 0);
        }
        __builtin_amdgcn_s_setprio(0);
        f32x16v p;
#pragma unroll
        for (int e = 0; e < 16; ++e) p[e] = p0[e] + p1[e];

        const bool diag = (kb == KBMAX);
        float rsum = 0.f;
#pragma unroll
        for (int reg = 0; reg < 16; ++reg) {
            if (diag) {
                const int kc = kb * 32 + (reg & 3) + 8 * (reg >> 2) + 4 * s;
                if (kc > qc) p[reg] = 0.f;
            }
            rsum += p[reg];
        }
        den += rsum;
#pragma unroll
        for (int kh = 0; kh < 2; ++kh) {
            const u32 pA_lo = cvtpk(p[8*kh + 0], p[8*kh + 1]);
            const u32 pA_hi = cvtpk(p[8*kh + 2], p[8*kh + 3]);
            const u32 pB_lo = cvtpk(p[8*kh + 4], p[8*kh + 5]);
            const u32 pB_hi = cvtpk(p[8*kh + 6], p[8*kh + 7]);
            const u32 X_lo = s ? pB_lo : pA_lo;
            const u32 X_hi = s ? pB_hi : pA_hi;
            const u32 Y_lo = s ? pA_lo : pB_lo;
            const u32 Y_hi = s ? pA_hi : pB_hi;
            const u32 sY_lo = __shfl_xor((int)Y_lo, 32);
            const u32 sY_hi = __shfl_xor((int)Y_hi, 32);
            u32 wq[4];
            wq[0] = s ? sY_lo : X_lo;
            wq[1] = s ? sY_hi : X_hi;
            wq[2] = s ? X_lo : sY_lo;
            wq[3] = s ? X_hi : sY_hi;
            s16x8 pa;
#pragma unroll
            for (int i = 0; i < 4; ++i) {
                pa[2*i]   = (short)(wq[i] & 0xffff);
                pa[2*i+1] = (short)(wq[i] >> 16);
            }
            __builtin_amdgcn_s_setprio(1);
            o0 = __builtin_amdgcn_mfma_f32_32x32x16_bf16(pa, vf[kh][0], o0, 0, 0, 0);
            o1 = __builtin_amdgcn_mfma_f32_32x32x16_bf16(pa, vf[kh][1], o1, 0, 0, 0);
            __builtin_amdgcn_s_setprio(0);
        }
    }
}

// ---------------------------------------------------------------------------
// Fused causal kernel. 2-wave blocks; wave w handles rf = pair / 7-pair.
// XCD-grouped: bid%8 = b-group. Intra via compile-time-unrolled template.
__global__ __launch_bounds__(128, 3) void causal_fused(
    const u16* __restrict__ PHIQ, const u16* __restrict__ PHIK,
    const u16* __restrict__ VPT, const u16* __restrict__ STBF,
    u16* __restrict__ ATT)
{
    const u32 bid = blockIdx.x;
    const int pair = (int)((bid >> 3) & 3);
    const int G  = (int)((bid >> 5) * 8 + (bid & 7));   // = c*64 + b
    const int b  = G & 63;
    const int c  = G >> 6;
    const int w  = threadIdx.x >> 6;
    const int rf = w ? (7 - pair) : pair;
    const int ri = rf >> 1, fi = rf & 1;
    const int lane = threadIdx.x & 63;
    const int l31 = lane & 31, s = lane >> 5;
    const size_t chunk0 = (size_t)b * 2048 + (size_t)c * 256;
    const u16* stb = STBF + (size_t)(b * 8 + c) * 16640;

    const int qc = ri * 64 + fi * 32 + l31;
    s16x8 qf[16];
    const u16* qp = PHIQ + (chunk0 + qc) * 256 + s * 8;
#pragma unroll
    for (int ds = 0; ds < 16; ++ds)
        qf[ds] = *(const s16x8*)(qp + ds * 16);

    f32x16v o[2], o2;
#pragma unroll
    for (int e = 0; e < 16; ++e) { o[0][e] = 0.f; o[1][e] = 0.f; o2[e] = 0.f; }
    float den = 0.f;

    // ---- inter: o += Q.S^T ; o2 += Q.z (den per D-row)
#pragma unroll
    for (int ds = 0; ds < 16; ++ds) {
        const s16x8 zf = *(const s16x8*)(stb + 16384 + ds * 16 + s * 8);
        o2 = __builtin_amdgcn_mfma_f32_32x32x16_bf16(qf[ds], zf, o2, 0, 0, 0);
#pragma unroll
        for (int fh = 0; fh < 2; ++fh) {
            const s16x8 sx = *(const s16x8*)(stb + (fh * 32 + l31) * 256 + ds * 16 + s * 8);
            o[fh] = __builtin_amdgcn_mfma_f32_32x32x16_bf16(qf[ds], sx, o[fh], 0, 0, 0);
        }
    }

    // ---- intra: compile-time kb trip count
    const u16* kbase = PHIK + chunk0 * 256;
    const u16* vbase = VPT + (size_t)b * 64 * 2048 + c * 256;
    const int kbmax = ri * 2 + fi;
    switch (kbmax) {
        case 0: intra_unit<0>(kbase, vbase, qf, qc, l31, s, o[0], o[1], den); break;
        case 1: intra_unit<1>(kbase, vbase, qf, qc, l31, s, o[0], o[1], den); break;
        case 2: intra_unit<2>(kbase, vbase, qf, qc, l31, s, o[0], o[1], den); break;
        case 3: intra_unit<3>(kbase, vbase, qf, qc, l31, s, o[0], o[1], den); break;
        case 4: intra_unit<4>(kbase, vbase, qf, qc, l31, s, o[0], o[1], den); break;
        case 5: intra_unit<5>(kbase, vbase, qf, qc, l31, s, o[0], o[1], den); break;
        case 6: intra_unit<6>(kbase, vbase, qf, qc, l31, s, o[0], o[1], den); break;
        default: intra_unit<7>(kbase, vbase, qf, qc, l31, s, o[0], o[1], den); break;
    }

    // ---- epilogue
    const float denT = den + __shfl_xor(den, 32);
#pragma unroll
    for (int reg = 0; reg < 16; ++reg) {
        const int q32 = (reg & 3) + 8 * (reg >> 2) + 4 * s;
        const float dv = o2[reg] + __shfl(denT, q32);
        const float inv = 1.f / (dv + 1e-6f);
        const int qrow = c * 256 + ri * 64 + fi * 32 + q32;
        const size_t abase = (size_t)qrow * 4096 + b * 64;
        ATT[abase + l31]      = f2bf(o[0][reg] * inv);
        ATT[abase + 32 + l31] = f2bf(o[1][reg] * inv);
    }
}

// ---------------------------------------------------------------------------
extern "C" void kernel_launch(void* const* d_in, const int* in_sizes, int n_in,
                              void* d_out, int out_size, void* d_ws, size_t ws_size,
                              hipStream_t stream)
{
    const float* query = (const float*)d_in[0];
    const float* key   = (const float*)d_in[1];
    const float* value = (const float*)d_in[2];
    const float* wq    = (const float*)d_in[3];
    const float* bq    = (const float*)d_in[4];
    const float* wk    = (const float*)d_in[5];
    const float* bk    = (const float*)d_in[6];
    const float* wv    = (const float*)d_in[7];
    const float* bv    = (const float*)d_in[8];
    const float* wo    = (const float*)d_in[9];
    const float* bo    = (const float*)d_in[10];
    const float* rm    = (const float*)d_in[11];
    float* out = (float*)d_out;

    // Workspace (227,278,848 B <= proven 235,929,600 B). attn overlays qp
    // (qp dead after rand_project; attn written by causal_fused afterwards).
    char* base = (char*)d_ws;
    u16* phiq = (u16*)(base);                    //  67,108,864
    u16* phik = (u16*)(base +  67108864);        //  67,108,864
    u16* vpt  = (u16*)(base + 134217728);        //  16,777,216
    u16* stbf = (u16*)(base + 150994944);        //  17,039,360
    u16* qp   = (u16*)(base + 168034304);        //  16,777,216 (-> attn overlay)
    u16* kp   = (u16*)(base + 184811520);        //  16,777,216
    u16* stc  = (u16*)(base + 201588736);        //  17,039,360
    u16* wbf  = (u16*)(base + 218628096);        //   8,388,608
    u16* rmb  = (u16*)(base + 227016704);        //     262,144
    u16* attn = qp;

    u16* wqb = wbf;
    u16* wkb = wbf + 1048576;
    u16* wvb = wbf + 2097152;
    u16* wob = wbf + 3145728;

    const dim3 blk(256);
    cvt_consts<<<dim3(512, 5), blk, 0, stream>>>(wq, wk, wv, wo, rm, wbf, rmb);
    gemm_qkv<<<dim3(64, 8, 3), blk, 0, stream>>>(query, key, value, wbf, bq, bk, bv, qp, kp, vpt);
    rand_project_mfma<<<dim3(16, 64, 2), blk, 0, stream>>>(qp, kp, rmb, phiq, phik);
    chunk_state_mfma<<<dim3(64, 16), blk, 0, stream>>>(phik, vpt, stc);
    prefix_scan<<<dim3(64, 65), blk, 0, stream>>>(stc, stbf);
    causal_fused<<<dim3(2048), dim3(128), 0, stream>>>(phiq, phik, vpt, stbf, attn);
    gemm_o<<<dim3(64, 8), blk, 0, stream>>>(attn, wob, bo, out);
}

// Round 12
// 289.088 us; speedup vs baseline: 1.3052x; 1.3052x over previous
//
#include <hip/hip_runtime.h>
#include <math.h>

// Dims: L=2048 N=4 E=1024 H=16 D=128 HD=64; 2D=256; M=L*N=8192; B=64
// phi natural (l,n,h,d) flat order == reference's scrambled (b,l',d) view.
// attn row mapping: flat l*4096 + b*64 + hd == (l*4+nb)*1024 + (h16*64+hd), b=nb*16+h16.
// Chunked causal: CHK=256, NC=8.

typedef unsigned short u16;
typedef unsigned int u32;
using f32x4v  = __attribute__((ext_vector_type(4))) float;
using f32x16v = __attribute__((ext_vector_type(16))) float;
using s16x8   = __attribute__((ext_vector_type(8))) short;

__device__ __forceinline__ float bf2f(u16 u) { return __uint_as_float(((u32)u) << 16); }
__device__ __forceinline__ u16 f2bf(float x) {
    u32 b = __float_as_uint(x);
    b += 0x7fff + ((b >> 16) & 1);          // RNE
    return (u16)(b >> 16);
}
__device__ __forceinline__ u32 cvtpk(float lo, float hi) {
    u32 r;
    asm("v_cvt_pk_bf16_f32 %0, %1, %2" : "=v"(r) : "v"(lo), "v"(hi));
    return r;
}
__device__ __forceinline__ float exp2f_hw(float x) {
    float r;
    asm("v_exp_f32 %0, %1" : "=v"(r) : "v"(x));
    return r;
}
__device__ __forceinline__ void gload_lds16(const void* g, void* l) {
    __builtin_amdgcn_global_load_lds(
        (const __attribute__((address_space(1))) void*)g,
        (__attribute__((address_space(3))) void*)l, 16, 0, 0);
}

// ---------------------------------------------------------------------------
// All f32->bf16 conversions in one launch: y = 0..3 weights, 4 rm, 5 query, 6 key
__global__ __launch_bounds__(256) void cvt_consts(
    const float* __restrict__ w0, const float* __restrict__ w1,
    const float* __restrict__ w2, const float* __restrict__ w3,
    const float* __restrict__ rm, const float* __restrict__ query,
    const float* __restrict__ key, u16* __restrict__ wqkv,
    u16* __restrict__ wob, u16* __restrict__ rmb,
    u16* __restrict__ xq, u16* __restrict__ xk)
{
    const int y = blockIdx.y;
    const float* src;
    u16* d;
    int nblk;
    switch (y) {
        case 0: src = w0; d = wqkv;            nblk = 512;  break;
        case 1: src = w1; d = wqkv + 1048576;  nblk = 512;  break;
        case 2: src = w2; d = wqkv + 2097152;  nblk = 512;  break;
        case 3: src = w3; d = wob;             nblk = 512;  break;
        case 4: src = rm; d = rmb;             nblk = 64;   break;
        case 5: src = query; d = xq;           nblk = 4096; break;
        default: src = key; d = xk;            nblk = 4096; break;
    }
    if ((int)blockIdx.x >= nblk) return;
    const size_t i = ((size_t)blockIdx.x * 256 + threadIdx.x) * 8;
    const float4 a = *(const float4*)(src + i);
    const float4 b = *(const float4*)(src + i + 4);
    u16 o[8] = {f2bf(a.x), f2bf(a.y), f2bf(a.z), f2bf(a.w),
                f2bf(b.x), f2bf(b.y), f2bf(b.z), f2bf(b.w)};
    *(uint4*)(d + i) = *(uint4*)o;
}

// ---------------------------------------------------------------------------
// QKV projection GEMM, one dispatch (z selects). z<2: A = bf16 (gload_lds,
// zero staging VALU). z==2: A = f32 value, reg-staged + converted (round-11
// verified path). B = bf16 weights via global_load_lds.
// z<2 -> bf16 row-major (qp/kp); z==2 -> vpt[(b*64+hd)*2048 + k].
__global__ __launch_bounds__(256) void gemm_qkv(
    const u16* __restrict__ XQ, const u16* __restrict__ XK, const float* __restrict__ Xv,
    const u16* __restrict__ WB, const float* __restrict__ bq, const float* __restrict__ bk,
    const float* __restrict__ bv, u16* __restrict__ qp, u16* __restrict__ kp, u16* __restrict__ vpt)
{
    __shared__ __align__(16) u16 As[4096];
    __shared__ __align__(16) u16 Bs[4096];
    const int z = blockIdx.z;
    const u16* Bw = WB + (size_t)z * 1048576;
    const float* bias = (z == 0) ? bq : (z == 1) ? bk : bv;

    const int t = threadIdx.x;
    const int m0 = blockIdx.x * 128, n0 = blockIdx.y * 128;
    const int wid = t >> 6, lane = t & 63;
    const int wr = wid >> 1, wc = wid & 1;
    const int l15 = lane & 15, l4 = lane >> 4;

    f32x4v acc[4][4];
#pragma unroll
    for (int i = 0; i < 4; ++i)
#pragma unroll
        for (int j = 0; j < 4; ++j)
#pragma unroll
            for (int e = 0; e < 4; ++e) acc[i][j][e] = 0.f;

    // B staging (gload_lds linear) — also A for z<2
    const int brow = wid * 32 + (lane >> 2);
    const int bcol = (lane & 3) * 8;
    const u16* gb0 = Bw + (size_t)(n0 + brow) * 1024 + bcol;
    const u16* gb1 = gb0 + 16 * 1024;
    u16* lb0 = &Bs[wid * 1024];
    u16* lb1 = lb0 + 512;
    const u16* XA = (z == 0) ? XQ : XK;
    const u16* ga0 = XA + (size_t)(m0 + brow) * 1024 + bcol;
    const u16* ga1 = ga0 + 16 * 1024;
    u16* la0 = &As[wid * 1024];
    u16* la1 = la0 + 512;
    // z==2: f32 A reg-staging map (2 threads/row, 16 f32 each) + XOR swizzle
    const int srow = t >> 1;
    const int scol = (t & 1) * 16;
    const int sx   = (srow >> 1) & 3;
    const int sl0  = (t & 1) * 2;
    u16* wa0 = &As[srow * 32 + ((sl0     ^ sx)) * 8];
    u16* wa1 = &As[srow * 32 + (((sl0+1) ^ sx)) * 8];
    const float* gsrcA = Xv + (size_t)(m0 + srow) * 1024 + scol;

    for (int k0 = 0; k0 < 1024; k0 += 32) {
        __syncthreads();
        gload_lds16(gb0 + k0, lb0);
        gload_lds16(gb1 + k0, lb1);
        if (z < 2) {
            gload_lds16(ga0 + k0, la0);
            gload_lds16(ga1 + k0, la1);
        } else {
            u16 ta[16];
#pragma unroll
            for (int q = 0; q < 4; ++q) {
                const float4 v = *(const float4*)(gsrcA + k0 + q * 4);
                ta[q*4+0] = f2bf(v.x); ta[q*4+1] = f2bf(v.y);
                ta[q*4+2] = f2bf(v.z); ta[q*4+3] = f2bf(v.w);
            }
            *(uint4*)wa0 = *(const uint4*)&ta[0];
            *(uint4*)wa1 = *(const uint4*)&ta[8];
        }
        __syncthreads();
        s16x8 af[4], bfr[4];
        if (z < 2) {
#pragma unroll
            for (int fi = 0; fi < 4; ++fi)
                af[fi] = *(const s16x8*)&As[(wr * 64 + fi * 16 + l15) * 32 + l4 * 8];
        } else {
#pragma unroll
            for (int fi = 0; fi < 4; ++fi) {
                const int r  = wr * 64 + fi * 16 + l15;
                const int sl = l4 ^ ((r >> 1) & 3);
                af[fi] = *(const s16x8*)&As[r * 32 + sl * 8];
            }
        }
#pragma unroll
        for (int fj = 0; fj < 4; ++fj)
            bfr[fj] = *(const s16x8*)&Bs[(wc * 64 + fj * 16 + l15) * 32 + l4 * 8];
#pragma unroll
        for (int fi = 0; fi < 4; ++fi)
#pragma unroll
            for (int fj = 0; fj < 4; ++fj)
                acc[fi][fj] = __builtin_amdgcn_mfma_f32_16x16x32_bf16(af[fi], bfr[fj], acc[fi][fj], 0, 0, 0);
    }

    u16* Cp = (z == 0) ? qp : (z == 1) ? kp : vpt;
    const int rl = l4 * 4, cl = l15;
    float bvals[4];
#pragma unroll
    for (int fj = 0; fj < 4; ++fj) bvals[fj] = bias[n0 + wc * 64 + fj * 16 + cl];
#pragma unroll
    for (int fi = 0; fi < 4; ++fi)
#pragma unroll
        for (int j = 0; j < 4; ++j) {
            const size_t m = m0 + wr * 64 + fi * 16 + rl + j;
#pragma unroll
            for (int fj = 0; fj < 4; ++fj) {
                const int n = n0 + wc * 64 + fj * 16 + cl;
                const float v = acc[fi][fj][j] + bvals[fj];
                if (z < 2) Cp[m * 1024 + n] = f2bf(v);
                else       Cp[((size_t)((m & 3) * 16 + (n >> 6)) * 64 + (n & 63)) * 2048 + (m >> 2)] = f2bf(v);
            }
        }
}

// ---------------------------------------------------------------------------
// Output GEMM: A bf16 (gload_lds), B bf16 weights (gload_lds), f32 out.
__global__ __launch_bounds__(256) void gemm_o(
    const u16* __restrict__ A, const u16* __restrict__ Bw,
    const float* __restrict__ bias, float* __restrict__ Cp)
{
    __shared__ __align__(16) u16 As[4096];
    __shared__ __align__(16) u16 Bs[4096];
    const int t = threadIdx.x;
    const int m0 = blockIdx.x * 128, n0 = blockIdx.y * 128;
    const int wid = t >> 6, lane = t & 63;
    const int wr = wid >> 1, wc = wid & 1;
    const int l15 = lane & 15, l4 = lane >> 4;

    f32x4v acc[4][4];
#pragma unroll
    for (int i = 0; i < 4; ++i)
#pragma unroll
        for (int j = 0; j < 4; ++j)
#pragma unroll
            for (int e = 0; e < 4; ++e) acc[i][j][e] = 0.f;

    const int srow = wid * 32 + (lane >> 2);
    const int scol = (lane & 3) * 8;
    const u16* ga0 = A  + (size_t)(m0 + srow) * 1024 + scol;
    const u16* ga1 = ga0 + 16 * 1024;
    const u16* gb0 = Bw + (size_t)(n0 + srow) * 1024 + scol;
    const u16* gb1 = gb0 + 16 * 1024;
    u16* la0 = &As[wid * 1024];
    u16* la1 = la0 + 512;
    u16* lb0 = &Bs[wid * 1024];
    u16* lb1 = lb0 + 512;

    for (int k0 = 0; k0 < 1024; k0 += 32) {
        __syncthreads();
        gload_lds16(ga0 + k0, la0);
        gload_lds16(ga1 + k0, la1);
        gload_lds16(gb0 + k0, lb0);
        gload_lds16(gb1 + k0, lb1);
        __syncthreads();
        s16x8 af[4], bfr[4];
#pragma unroll
        for (int fi = 0; fi < 4; ++fi)
            af[fi] = *(const s16x8*)&As[(wr * 64 + fi * 16 + l15) * 32 + l4 * 8];
#pragma unroll
        for (int fj = 0; fj < 4; ++fj)
            bfr[fj] = *(const s16x8*)&Bs[(wc * 64 + fj * 16 + l15) * 32 + l4 * 8];
#pragma unroll
        for (int fi = 0; fi < 4; ++fi)
#pragma unroll
            for (int fj = 0; fj < 4; ++fj)
                acc[fi][fj] = __builtin_amdgcn_mfma_f32_16x16x32_bf16(af[fi], bfr[fj], acc[fi][fj], 0, 0, 0);
    }

    const int rl = l4 * 4, cl = l15;
    float bvals[4];
#pragma unroll
    for (int fj = 0; fj < 4; ++fj) bvals[fj] = bias[n0 + wc * 64 + fj * 16 + cl];
#pragma unroll
    for (int fi = 0; fi < 4; ++fi)
#pragma unroll
        for (int j = 0; j < 4; ++j) {
            const size_t m = m0 + wr * 64 + fi * 16 + rl + j;
#pragma unroll
            for (int fj = 0; fj < 4; ++fj) {
                const int n = n0 + wc * 64 + fj * 16 + cl;
                Cp[m * 1024 + n] = acc[fi][fj][j] + bvals[fj];
            }
        }
}

// ---------------------------------------------------------------------------
// Random projection via MFMA (round-10 verified).
__global__ __launch_bounds__(256) void rand_project_mfma(
    const u16* __restrict__ QP, const u16* __restrict__ KP,
    const u16* __restrict__ RMB, u16* __restrict__ PHIQ, u16* __restrict__ PHIK)
{
    const u16* X  = (blockIdx.z == 0) ? QP : KP;
    u16* PHI      = (blockIdx.z == 0) ? PHIQ : PHIK;
    __shared__ __align__(16) u16 Xs[128 * 72];
    __shared__ __align__(16) u16 RMs[128 * 72];
    __shared__ float rsl_lds[128];
    const int h  = blockIdx.x;
    const int r0 = blockIdx.y * 128;
    const int t  = threadIdx.x;
    const int w  = t >> 6, lane = t & 63;
    const int l15 = lane & 15, l4 = lane >> 4;

    float sq[4];
#pragma unroll
    for (int i = 0; i < 4; ++i) {
        const int lin = t + i * 256;
        const int row = lin >> 3, oct = lin & 7;
        const uint4 xv = *(const uint4*)(X + (size_t)(r0 + row) * 1024 + h * 64 + oct * 8);
        *(uint4*)&Xs[row * 72 + oct * 8] = xv;
        const u16* pv = (const u16*)&xv;
        float s = 0.f;
#pragma unroll
        for (int e = 0; e < 8; ++e) { const float f = bf2f(pv[e]); s += f * f; }
        sq[i] = s;
        const uint4 rv = *(const uint4*)(RMB + (size_t)h * 8192 + lin * 8);
        *(uint4*)&RMs[row * 72 + oct * 8] = rv;
    }
#pragma unroll
    for (int i = 0; i < 4; ++i) {
        sq[i] += __shfl_xor(sq[i], 1);
        sq[i] += __shfl_xor(sq[i], 2);
        sq[i] += __shfl_xor(sq[i], 4);
        if ((t & 7) == 0)
            rsl_lds[(t >> 3) + i * 32] = 1.4426950408889634f / fmaxf(sqrtf(sq[i]), 1e-12f);
    }
    __syncthreads();

    const int wr = (w >> 1) * 64, wc = (w & 1) * 64;
    f32x4v acc[4][4];
#pragma unroll
    for (int i = 0; i < 4; ++i)
#pragma unroll
        for (int j = 0; j < 4; ++j)
#pragma unroll
            for (int e = 0; e < 4; ++e) acc[i][j][e] = 0.f;
#pragma unroll
    for (int ks = 0; ks < 2; ++ks) {
        s16x8 af[4], bfr[4];
#pragma unroll
        for (int fi = 0; fi < 4; ++fi)
            af[fi] = *(const s16x8*)&Xs[(wr + fi * 16 + l15) * 72 + ks * 32 + l4 * 8];
#pragma unroll
        for (int fj = 0; fj < 4; ++fj)
            bfr[fj] = *(const s16x8*)&RMs[(wc + fj * 16 + l15) * 72 + ks * 32 + l4 * 8];
#pragma unroll
        for (int fi = 0; fi < 4; ++fi)
#pragma unroll
            for (int fj = 0; fj < 4; ++fj)
                acc[fi][fj] = __builtin_amdgcn_mfma_f32_16x16x32_bf16(af[fi], bfr[fj], acc[fi][fj], 0, 0, 0);
    }

#pragma unroll
    for (int fi = 0; fi < 4; ++fi)
#pragma unroll
        for (int reg = 0; reg < 4; ++reg) {
            const int row = wr + fi * 16 + l4 * 4 + reg;
            const float rsl = rsl_lds[row];
            const size_t base = ((size_t)(r0 + row) * 16 + h) * 256;
#pragma unroll
            for (int fj = 0; fj < 4; ++fj) {
                const int d = wc + fj * 16 + l15;
                const float arg = acc[fi][fj][reg] * rsl;
                PHI[base + d]       = f2bf(exp2f_hw(arg - 4.f));
                PHI[base + 128 + d] = f2bf(exp2f_hw(-arg - 4.f));
            }
        }
}

// ---------------------------------------------------------------------------
// Chunk state via MFMA -> bf16 chunk sums (stc).
__global__ __launch_bounds__(256) void chunk_state_mfma(
    const u16* __restrict__ PHIK, const u16* __restrict__ VPT, u16* __restrict__ STC)
{
    __shared__ __align__(16) u16 Ks[64 * 136];
    __shared__ float zlds[16][132];
    const int b = blockIdx.x;
    const int c = blockIdx.y >> 1;
    const int dh = blockIdx.y & 1;
    const int t = threadIdx.x;
    const int wid = t >> 6, lane = t & 63;
    const int l15 = lane & 15, l4 = lane >> 4;
    const int wr = wid >> 1, wc = wid & 1;

    const size_t R0 = (size_t)b * 2048 + (size_t)c * 256;
    const int rgrp = t >> 4, d08 = (t & 15) * 8;

    float zpart[8];
#pragma unroll
    for (int i = 0; i < 8; ++i) zpart[i] = 0.f;

    f32x4v acc[2][4];
#pragma unroll
    for (int i = 0; i < 2; ++i)
#pragma unroll
        for (int j = 0; j < 4; ++j)
#pragma unroll
            for (int e = 0; e < 4; ++e) acc[i][j][e] = 0.f;

    for (int stage = 0; stage < 4; ++stage) {
        __syncthreads();
#pragma unroll
        for (int j = 0; j < 4; ++j) {
            const int r = rgrp + 16 * j;
            const uint4 v = *(const uint4*)(PHIK + (R0 + stage * 64 + r) * 256 + dh * 128 + d08);
            const int x = ((r >> 3) & 3) << 1;
            *(uint4*)&Ks[r * 136 + (((d08 >> 3) ^ x) << 3)] = v;
            const u16* pv = (const u16*)&v;
#pragma unroll
            for (int i = 0; i < 8; ++i) zpart[i] += bf2f(pv[i]);
        }
        __syncthreads();
#pragma unroll
        for (int ks = 0; ks < 2; ++ks) {
            const int xk = ((ks * 4 + l4) & 3) << 1;
            const int r0 = ks * 32 + l4 * 8;
            s16x8 af[2], bk[4];
#pragma unroll
            for (int fi = 0; fi < 2; ++fi) {
                const int h = wr * 32 + fi * 16 + l15;
                af[fi] = *(const s16x8*)(VPT + ((size_t)b * 64 + h) * 2048 + c * 256 + stage * 64 + ks * 32 + l4 * 8);
            }
#pragma unroll
            for (int fj = 0; fj < 4; ++fj) {
                const int d = wc * 64 + fj * 16 + l15;
                const int colk = (((d >> 3) ^ xk) << 3) + (d & 7);
#pragma unroll
                for (int e = 0; e < 8; ++e)
                    bk[fj][e] = (short)Ks[(r0 + e) * 136 + colk];
            }
#pragma unroll
            for (int fi = 0; fi < 2; ++fi)
#pragma unroll
                for (int fj = 0; fj < 4; ++fj)
                    acc[fi][fj] = __builtin_amdgcn_mfma_f32_16x16x32_bf16(af[fi], bk[fj], acc[fi][fj], 0, 0, 0);
        }
    }
    __syncthreads();
    *(float4*)&zlds[rgrp][d08]     = *(float4*)&zpart[0];
    *(float4*)&zlds[rgrp][d08 + 4] = *(float4*)&zpart[4];
    __syncthreads();
    u16* st = STC + (size_t)(b * 8 + c) * 16640;
    if (t < 128) {
        float z = 0.f;
#pragma unroll
        for (int g = 0; g < 16; ++g) z += zlds[g][t];
        st[16384 + dh * 128 + t] = f2bf(z);
    }
#pragma unroll
    for (int fi = 0; fi < 2; ++fi)
#pragma unroll
        for (int reg = 0; reg < 4; ++reg) {
            const int h = wr * 32 + fi * 16 + l4 * 4 + reg;
#pragma unroll
            for (int fj = 0; fj < 4; ++fj) {
                const int d = dh * 128 + wc * 64 + fj * 16 + l15;
                st[(size_t)h * 256 + d] = f2bf(acc[fi][fj][reg]);
            }
        }
}

// ---------------------------------------------------------------------------
// Exclusive prefix over 8 chunks (f32 accumulation of bf16 chunk sums).
__global__ void prefix_scan(const u16* __restrict__ STC, u16* __restrict__ STBF)
{
    const int b = blockIdx.x;
    const int e = blockIdx.y * 256 + threadIdx.x;
    if (e >= 16640) return;
    float run = 0.f;
#pragma unroll
    for (int c = 0; c < 8; ++c) {
        const size_t idx = (size_t)(b * 8 + c) * 16640 + e;
        const float v = bf2f(STC[idx]);
        STBF[idx] = f2bf(run);
        run += v;
    }
}

// ---------------------------------------------------------------------------
// Fused causal kernel — round-10 version (known-good, 78 us). 2-wave blocks;
// wave w handles rf = pair / 7-pair (balanced). XCD-grouped: bid%8 = b-group.
__global__ __launch_bounds__(128) void causal_fused(
    const u16* __restrict__ PHIQ, const u16* __restrict__ PHIK,
    const u16* __restrict__ VPT, const u16* __restrict__ STBF,
    u16* __restrict__ ATT)
{
    const u32 bid = blockIdx.x;
    const int pair = (int)((bid >> 3) & 3);
    const int G  = (int)((bid >> 5) * 8 + (bid & 7));   // = c*64 + b
    const int b  = G & 63;
    const int c  = G >> 6;
    const int w  = threadIdx.x >> 6;
    const int rf = w ? (7 - pair) : pair;
    const int ri = rf >> 1, fi = rf & 1;
    const int lane = threadIdx.x & 63;
    const int l31 = lane & 31, s = lane >> 5;
    const size_t chunk0 = (size_t)b * 2048 + (size_t)c * 256;
    const u16* stb = STBF + (size_t)(b * 8 + c) * 16640;

    const int qc = ri * 64 + fi * 32 + l31;
    s16x8 qf[16];
    const u16* qp = PHIQ + (chunk0 + qc) * 256 + s * 8;
#pragma unroll
    for (int ds = 0; ds < 16; ++ds)
        qf[ds] = *(const s16x8*)(qp + ds * 16);

    f32x16v o[2], o2;
#pragma unroll
    for (int e = 0; e < 16; ++e) { o[0][e] = 0.f; o[1][e] = 0.f; o2[e] = 0.f; }
    float den = 0.f;

    // ---- inter: o += Q.S^T ; o2 += Q.z (den per D-row)
#pragma unroll
    for (int ds = 0; ds < 16; ++ds) {
        const s16x8 zf = *(const s16x8*)(stb + 16384 + ds * 16 + s * 8);
        o2 = __builtin_amdgcn_mfma_f32_32x32x16_bf16(qf[ds], zf, o2, 0, 0, 0);
#pragma unroll
        for (int fh = 0; fh < 2; ++fh) {
            const s16x8 sx = *(const s16x8*)(stb + (fh * 32 + l31) * 256 + ds * 16 + s * 8);
            o[fh] = __builtin_amdgcn_mfma_f32_32x32x16_bf16(qf[ds], sx, o[fh], 0, 0, 0);
        }
    }

    // ---- intra: swapped QK^T over 32-row k-blocks
    const int kbmax = ri * 2 + fi;
    for (int kb = 0; kb <= kbmax; ++kb) {
        s16x8 vf[2][2];
#pragma unroll
        for (int kh = 0; kh < 2; ++kh)
#pragma unroll
            for (int fh = 0; fh < 2; ++fh)
                vf[kh][fh] = *(const s16x8*)(VPT + ((size_t)b * 64 + fh * 32 + l31) * 2048
                                             + c * 256 + kb * 32 + kh * 16 + s * 8);
        f32x16v p0, p1;
#pragma unroll
        for (int e = 0; e < 16; ++e) { p0[e] = 0.f; p1[e] = 0.f; }
        const u16* kptr = PHIK + (chunk0 + kb * 32 + l31) * 256 + s * 8;
#pragma unroll
        for (int ds = 0; ds < 8; ++ds) {
            const s16x8 kf0 = *(const s16x8*)(kptr + (2 * ds) * 16);
            const s16x8 kf1 = *(const s16x8*)(kptr + (2 * ds + 1) * 16);
            p0 = __builtin_amdgcn_mfma_f32_32x32x16_bf16(kf0, qf[2 * ds],     p0, 0, 0, 0);
            p1 = __builtin_amdgcn_mfma_f32_32x32x16_bf16(kf1, qf[2 * ds + 1], p1, 0, 0, 0);
        }
        f32x16v p;
#pragma unroll
        for (int e = 0; e < 16; ++e) p[e] = p0[e] + p1[e];

        const bool diag = (kb == kbmax);
        float rsum = 0.f;
#pragma unroll
        for (int reg = 0; reg < 16; ++reg) {
            if (diag) {
                const int kc = kb * 32 + (reg & 3) + 8 * (reg >> 2) + 4 * s;
                if (kc > qc) p[reg] = 0.f;
            }
            rsum += p[reg];
        }
        den += rsum;
#pragma unroll
        for (int kh = 0; kh < 2; ++kh) {
            const u32 pA_lo = cvtpk(p[8*kh + 0], p[8*kh + 1]);
            const u32 pA_hi = cvtpk(p[8*kh + 2], p[8*kh + 3]);
            const u32 pB_lo = cvtpk(p[8*kh + 4], p[8*kh + 5]);
            const u32 pB_hi = cvtpk(p[8*kh + 6], p[8*kh + 7]);
            const u32 X_lo = s ? pB_lo : pA_lo;
            const u32 X_hi = s ? pB_hi : pA_hi;
            const u32 Y_lo = s ? pA_lo : pB_lo;
            const u32 Y_hi = s ? pA_hi : pB_hi;
            const u32 sY_lo = __shfl_xor((int)Y_lo, 32);
            const u32 sY_hi = __shfl_xor((int)Y_hi, 32);
            u32 wq[4];
            wq[0] = s ? sY_lo : X_lo;
            wq[1] = s ? sY_hi : X_hi;
            wq[2] = s ? X_lo : sY_lo;
            wq[3] = s ? X_hi : sY_hi;
            s16x8 pa;
#pragma unroll
            for (int i = 0; i < 4; ++i) {
                pa[2*i]   = (short)(wq[i] & 0xffff);
                pa[2*i+1] = (short)(wq[i] >> 16);
            }
            o[0] = __builtin_amdgcn_mfma_f32_32x32x16_bf16(pa, vf[kh][0], o[0], 0, 0, 0);
            o[1] = __builtin_amdgcn_mfma_f32_32x32x16_bf16(pa, vf[kh][1], o[1], 0, 0, 0);
        }
    }

    // ---- epilogue
    const float denT = den + __shfl_xor(den, 32);
#pragma unroll
    for (int reg = 0; reg < 16; ++reg) {
        const int q32 = (reg & 3) + 8 * (reg >> 2) + 4 * s;
        const float dv = o2[reg] + __shfl(denT, q32);
        const float inv = 1.f / (dv + 1e-6f);
        const int qrow = c * 256 + ri * 64 + fi * 32 + q32;
        const size_t abase = (size_t)qrow * 4096 + b * 64;
        ATT[abase + l31]      = f2bf(o[0][reg] * inv);
        ATT[abase + 32 + l31] = f2bf(o[1][reg] * inv);
    }
}

// ---------------------------------------------------------------------------
extern "C" void kernel_launch(void* const* d_in, const int* in_sizes, int n_in,
                              void* d_out, int out_size, void* d_ws, size_t ws_size,
                              hipStream_t stream)
{
    const float* query = (const float*)d_in[0];
    const float* key   = (const float*)d_in[1];
    const float* value = (const float*)d_in[2];
    const float* wq    = (const float*)d_in[3];
    const float* bq    = (const float*)d_in[4];
    const float* wk    = (const float*)d_in[5];
    const float* bk    = (const float*)d_in[6];
    const float* wv    = (const float*)d_in[7];
    const float* bv    = (const float*)d_in[8];
    const float* wo    = (const float*)d_in[9];
    const float* bo    = (const float*)d_in[10];
    const float* rm    = (const float*)d_in[11];
    float* out = (float*)d_out;

    // Workspace (220,987,392 B <= proven 235,929,600 B). Overlays (ordered):
    //   wqkv lives in phiq head (dead before rand_project writes phiq)
    //   xq/xk overlay the stc/stbf region (dead after gemm_qkv; stc/stbf written later)
    //   attn overlays qp (dead after rand_project)
    char* base = (char*)d_ws;
    u16* phiq = (u16*)(base);                    //  67,108,864
    u16* phik = (u16*)(base +  67108864);        //  67,108,864
    u16* vpt  = (u16*)(base + 134217728);        //  16,777,216
    u16* qp   = (u16*)(base + 150994944);        //  16,777,216 (-> attn overlay)
    u16* kp   = (u16*)(base + 167772160);        //  16,777,216
    u16* stc  = (u16*)(base + 184549376);        //  17,039,360
    u16* stbf = (u16*)(base + 201588736);        //  17,039,360 (ends 218,628,096)
    u16* xq   = (u16*)(base + 184549376);        //  16,777,216 (overlay stc)
    u16* xk   = (u16*)(base + 201326592);        //  16,777,216 (overlay stc/stbf)
    u16* wob  = (u16*)(base + 218628096);        //   2,097,152
    u16* rmb  = (u16*)(base + 220725248);        //     262,144 (ends 220,987,392)
    u16* wqkv = phiq;                            //   6,291,456 (phiq head overlay)
    u16* attn = qp;

    const dim3 blk(256);
    cvt_consts<<<dim3(4096, 7), blk, 0, stream>>>(wq, wk, wv, wo, rm, query, key,
                                                  wqkv, wob, rmb, xq, xk);
    gemm_qkv<<<dim3(64, 8, 3), blk, 0, stream>>>(xq, xk, value, wqkv, bq, bk, bv, qp, kp, vpt);
    rand_project_mfma<<<dim3(16, 64, 2), blk, 0, stream>>>(qp, kp, rmb, phiq, phik);
    chunk_state_mfma<<<dim3(64, 16), blk, 0, stream>>>(phik, vpt, stc);
    prefix_scan<<<dim3(64, 65), blk, 0, stream>>>(stc, stbf);
    causal_fused<<<dim3(2048), dim3(128), 0, stream>>>(phiq, phik, vpt, stbf, attn);
    gemm_o<<<dim3(64, 8), blk, 0, stream>>>(attn, wob, bo, out);
}

// Round 13
// 285.661 us; speedup vs baseline: 1.3208x; 1.0120x over previous
//
#include <hip/hip_runtime.h>
#include <math.h>

// Dims: L=2048 N=4 E=1024 H=16 D=128 HD=64; 2D=256; M=L*N=8192; B=64
// phi natural (l,n,h,d) flat order == reference's scrambled (b,l',d) view.
// attn row mapping: flat l*4096 + b*64 + hd == (l*4+nb)*1024 + (h16*64+hd), b=nb*16+h16.
// Chunked causal: CHK=256, NC=8.
// GEMM LDS: linear dest via global_load_lds + PRE-SWIZZLED global source column
// (rule #21): phys slot sl at row r holds logical col sl^((r>>1)&3); reads XOR the
// same -> 2-way bank access (free) instead of 8-way.

typedef unsigned short u16;
typedef unsigned int u32;
using f32x4v  = __attribute__((ext_vector_type(4))) float;
using f32x16v = __attribute__((ext_vector_type(16))) float;
using s16x8   = __attribute__((ext_vector_type(8))) short;

__device__ __forceinline__ float bf2f(u16 u) { return __uint_as_float(((u32)u) << 16); }
__device__ __forceinline__ u16 f2bf(float x) {
    u32 b = __float_as_uint(x);
    b += 0x7fff + ((b >> 16) & 1);          // RNE
    return (u16)(b >> 16);
}
__device__ __forceinline__ u32 cvtpk(float lo, float hi) {
    u32 r;
    asm("v_cvt_pk_bf16_f32 %0, %1, %2" : "=v"(r) : "v"(lo), "v"(hi));
    return r;
}
__device__ __forceinline__ float exp2f_hw(float x) {
    float r;
    asm("v_exp_f32 %0, %1" : "=v"(r) : "v"(x));
    return r;
}
__device__ __forceinline__ void gload_lds16(const void* g, void* l) {
    __builtin_amdgcn_global_load_lds(
        (const __attribute__((address_space(1))) void*)g,
        (__attribute__((address_space(3))) void*)l, 16, 0, 0);
}

// ---------------------------------------------------------------------------
// All f32->bf16 conversions in one launch: y = 0..3 weights, 4 rm, 5 query, 6 key
__global__ __launch_bounds__(256) void cvt_consts(
    const float* __restrict__ w0, const float* __restrict__ w1,
    const float* __restrict__ w2, const float* __restrict__ w3,
    const float* __restrict__ rm, const float* __restrict__ query,
    const float* __restrict__ key, u16* __restrict__ wqkv,
    u16* __restrict__ wob, u16* __restrict__ rmb,
    u16* __restrict__ xq, u16* __restrict__ xk)
{
    const int y = blockIdx.y;
    const float* src;
    u16* d;
    int nblk;
    switch (y) {
        case 0: src = w0; d = wqkv;            nblk = 512;  break;
        case 1: src = w1; d = wqkv + 1048576;  nblk = 512;  break;
        case 2: src = w2; d = wqkv + 2097152;  nblk = 512;  break;
        case 3: src = w3; d = wob;             nblk = 512;  break;
        case 4: src = rm; d = rmb;             nblk = 64;   break;
        case 5: src = query; d = xq;           nblk = 4096; break;
        default: src = key; d = xk;            nblk = 4096; break;
    }
    if ((int)blockIdx.x >= nblk) return;
    const size_t i = ((size_t)blockIdx.x * 256 + threadIdx.x) * 8;
    const float4 a = *(const float4*)(src + i);
    const float4 b = *(const float4*)(src + i + 4);
    u16 o[8] = {f2bf(a.x), f2bf(a.y), f2bf(a.z), f2bf(a.w),
                f2bf(b.x), f2bf(b.y), f2bf(b.z), f2bf(b.w)};
    *(uint4*)(d + i) = *(uint4*)o;
}

// ---------------------------------------------------------------------------
// QKV projection GEMM, one dispatch (z selects). z<2: A = bf16 via swizzled-source
// gload_lds. z==2: A = f32 value, reg-staged + converted (writes same swizzle).
// B = bf16 weights via swizzled-source gload_lds.
// z<2 -> bf16 row-major (qp/kp); z==2 -> vpt[(b*64+hd)*2048 + k].
__global__ __launch_bounds__(256) void gemm_qkv(
    const u16* __restrict__ XQ, const u16* __restrict__ XK, const float* __restrict__ Xv,
    const u16* __restrict__ WB, const float* __restrict__ bq, const float* __restrict__ bk,
    const float* __restrict__ bv, u16* __restrict__ qp, u16* __restrict__ kp, u16* __restrict__ vpt)
{
    __shared__ __align__(16) u16 As[4096];
    __shared__ __align__(16) u16 Bs[4096];
    const int z = blockIdx.z;
    const u16* Bw = WB + (size_t)z * 1048576;
    const float* bias = (z == 0) ? bq : (z == 1) ? bk : bv;

    const int t = threadIdx.x;
    const int m0 = blockIdx.x * 128, n0 = blockIdx.y * 128;
    const int wid = t >> 6, lane = t & 63;
    const int wr = wid >> 1, wc = wid & 1;
    const int l15 = lane & 15, l4 = lane >> 4;

    f32x4v acc[4][4];
#pragma unroll
    for (int i = 0; i < 4; ++i)
#pragma unroll
        for (int j = 0; j < 4; ++j)
#pragma unroll
            for (int e = 0; e < 4; ++e) acc[i][j][e] = 0.f;

    // gload_lds staging: wave wid rows [wid*32, +32), lane -> row wid*32+(l>>2),
    // phys slot (l&3). Pre-swizzled source col: (slot ^ xr)*8, xr = ((row>>1)&3)
    // (invariant under row+16). LDS dest stays linear.
    const int brow = wid * 32 + (lane >> 2);
    const int xr   = (brow >> 1) & 3;
    const int scol2 = (((lane & 3) ^ xr)) * 8;
    const u16* gb0 = Bw + (size_t)(n0 + brow) * 1024 + scol2;
    const u16* gb1 = gb0 + 16 * 1024;
    u16* lb0 = &Bs[wid * 1024];
    u16* lb1 = lb0 + 512;
    const u16* XA = (z == 0) ? XQ : XK;
    const u16* ga0 = XA + (size_t)(m0 + brow) * 1024 + scol2;
    const u16* ga1 = ga0 + 16 * 1024;
    u16* la0 = &As[wid * 1024];
    u16* la1 = la0 + 512;
    // z==2: f32 A reg-staging map (2 threads/row, 16 f32 each) + same XOR swizzle
    const int srow = t >> 1;
    const int scol = (t & 1) * 16;
    const int sx   = (srow >> 1) & 3;
    const int sl0  = (t & 1) * 2;
    u16* wa0 = &As[srow * 32 + ((sl0     ^ sx)) * 8];
    u16* wa1 = &As[srow * 32 + (((sl0+1) ^ sx)) * 8];
    const float* gsrcA = Xv + (size_t)(m0 + srow) * 1024 + scol;

    for (int k0 = 0; k0 < 1024; k0 += 32) {
        __syncthreads();
        gload_lds16(gb0 + k0, lb0);
        gload_lds16(gb1 + k0, lb1);
        if (z < 2) {
            gload_lds16(ga0 + k0, la0);
            gload_lds16(ga1 + k0, la1);
        } else {
            u16 ta[16];
#pragma unroll
            for (int q = 0; q < 4; ++q) {
                const float4 v = *(const float4*)(gsrcA + k0 + q * 4);
                ta[q*4+0] = f2bf(v.x); ta[q*4+1] = f2bf(v.y);
                ta[q*4+2] = f2bf(v.z); ta[q*4+3] = f2bf(v.w);
            }
            *(uint4*)wa0 = *(const uint4*)&ta[0];
            *(uint4*)wa1 = *(const uint4*)&ta[8];
        }
        __syncthreads();
        s16x8 af[4], bfr[4];
#pragma unroll
        for (int fi = 0; fi < 4; ++fi) {
            const int r  = wr * 64 + fi * 16 + l15;
            const int sl = l4 ^ ((r >> 1) & 3);
            af[fi] = *(const s16x8*)&As[r * 32 + sl * 8];
        }
#pragma unroll
        for (int fj = 0; fj < 4; ++fj) {
            const int r  = wc * 64 + fj * 16 + l15;
            const int sl = l4 ^ ((r >> 1) & 3);
            bfr[fj] = *(const s16x8*)&Bs[r * 32 + sl * 8];
        }
#pragma unroll
        for (int fi = 0; fi < 4; ++fi)
#pragma unroll
            for (int fj = 0; fj < 4; ++fj)
                acc[fi][fj] = __builtin_amdgcn_mfma_f32_16x16x32_bf16(af[fi], bfr[fj], acc[fi][fj], 0, 0, 0);
    }

    u16* Cp = (z == 0) ? qp : (z == 1) ? kp : vpt;
    const int rl = l4 * 4, cl = l15;
    float bvals[4];
#pragma unroll
    for (int fj = 0; fj < 4; ++fj) bvals[fj] = bias[n0 + wc * 64 + fj * 16 + cl];
#pragma unroll
    for (int fi = 0; fi < 4; ++fi)
#pragma unroll
        for (int j = 0; j < 4; ++j) {
            const size_t m = m0 + wr * 64 + fi * 16 + rl + j;
#pragma unroll
            for (int fj = 0; fj < 4; ++fj) {
                const int n = n0 + wc * 64 + fj * 16 + cl;
                const float v = acc[fi][fj][j] + bvals[fj];
                if (z < 2) Cp[m * 1024 + n] = f2bf(v);
                else       Cp[((size_t)((m & 3) * 16 + (n >> 6)) * 64 + (n & 63)) * 2048 + (m >> 2)] = f2bf(v);
            }
        }
}

// ---------------------------------------------------------------------------
// Output GEMM: A bf16 + B bf16 via swizzled-source gload_lds, f32 out.
__global__ __launch_bounds__(256) void gemm_o(
    const u16* __restrict__ A, const u16* __restrict__ Bw,
    const float* __restrict__ bias, float* __restrict__ Cp)
{
    __shared__ __align__(16) u16 As[4096];
    __shared__ __align__(16) u16 Bs[4096];
    const int t = threadIdx.x;
    const int m0 = blockIdx.x * 128, n0 = blockIdx.y * 128;
    const int wid = t >> 6, lane = t & 63;
    const int wr = wid >> 1, wc = wid & 1;
    const int l15 = lane & 15, l4 = lane >> 4;

    f32x4v acc[4][4];
#pragma unroll
    for (int i = 0; i < 4; ++i)
#pragma unroll
        for (int j = 0; j < 4; ++j)
#pragma unroll
            for (int e = 0; e < 4; ++e) acc[i][j][e] = 0.f;

    const int brow = wid * 32 + (lane >> 2);
    const int xr   = (brow >> 1) & 3;
    const int scol2 = (((lane & 3) ^ xr)) * 8;
    const u16* ga0 = A  + (size_t)(m0 + brow) * 1024 + scol2;
    const u16* ga1 = ga0 + 16 * 1024;
    const u16* gb0 = Bw + (size_t)(n0 + brow) * 1024 + scol2;
    const u16* gb1 = gb0 + 16 * 1024;
    u16* la0 = &As[wid * 1024];
    u16* la1 = la0 + 512;
    u16* lb0 = &Bs[wid * 1024];
    u16* lb1 = lb0 + 512;

    for (int k0 = 0; k0 < 1024; k0 += 32) {
        __syncthreads();
        gload_lds16(ga0 + k0, la0);
        gload_lds16(ga1 + k0, la1);
        gload_lds16(gb0 + k0, lb0);
        gload_lds16(gb1 + k0, lb1);
        __syncthreads();
        s16x8 af[4], bfr[4];
#pragma unroll
        for (int fi = 0; fi < 4; ++fi) {
            const int r  = wr * 64 + fi * 16 + l15;
            const int sl = l4 ^ ((r >> 1) & 3);
            af[fi] = *(const s16x8*)&As[r * 32 + sl * 8];
        }
#pragma unroll
        for (int fj = 0; fj < 4; ++fj) {
            const int r  = wc * 64 + fj * 16 + l15;
            const int sl = l4 ^ ((r >> 1) & 3);
            bfr[fj] = *(const s16x8*)&Bs[r * 32 + sl * 8];
        }
#pragma unroll
        for (int fi = 0; fi < 4; ++fi)
#pragma unroll
            for (int fj = 0; fj < 4; ++fj)
                acc[fi][fj] = __builtin_amdgcn_mfma_f32_16x16x32_bf16(af[fi], bfr[fj], acc[fi][fj], 0, 0, 0);
    }

    const int rl = l4 * 4, cl = l15;
    float bvals[4];
#pragma unroll
    for (int fj = 0; fj < 4; ++fj) bvals[fj] = bias[n0 + wc * 64 + fj * 16 + cl];
#pragma unroll
    for (int fi = 0; fi < 4; ++fi)
#pragma unroll
        for (int j = 0; j < 4; ++j) {
            const size_t m = m0 + wr * 64 + fi * 16 + rl + j;
#pragma unroll
            for (int fj = 0; fj < 4; ++fj) {
                const int n = n0 + wc * 64 + fj * 16 + cl;
                Cp[m * 1024 + n] = acc[fi][fj][j] + bvals[fj];
            }
        }
}

// ---------------------------------------------------------------------------
// Random projection via MFMA (round-10 verified).
__global__ __launch_bounds__(256) void rand_project_mfma(
    const u16* __restrict__ QP, const u16* __restrict__ KP,
    const u16* __restrict__ RMB, u16* __restrict__ PHIQ, u16* __restrict__ PHIK)
{
    const u16* X  = (blockIdx.z == 0) ? QP : KP;
    u16* PHI      = (blockIdx.z == 0) ? PHIQ : PHIK;
    __shared__ __align__(16) u16 Xs[128 * 72];
    __shared__ __align__(16) u16 RMs[128 * 72];
    __shared__ float rsl_lds[128];
    const int h  = blockIdx.x;
    const int r0 = blockIdx.y * 128;
    const int t  = threadIdx.x;
    const int w  = t >> 6, lane = t & 63;
    const int l15 = lane & 15, l4 = lane >> 4;

    float sq[4];
#pragma unroll
    for (int i = 0; i < 4; ++i) {
        const int lin = t + i * 256;
        const int row = lin >> 3, oct = lin & 7;
        const uint4 xv = *(const uint4*)(X + (size_t)(r0 + row) * 1024 + h * 64 + oct * 8);
        *(uint4*)&Xs[row * 72 + oct * 8] = xv;
        const u16* pv = (const u16*)&xv;
        float s = 0.f;
#pragma unroll
        for (int e = 0; e < 8; ++e) { const float f = bf2f(pv[e]); s += f * f; }
        sq[i] = s;
        const uint4 rv = *(const uint4*)(RMB + (size_t)h * 8192 + lin * 8);
        *(uint4*)&RMs[row * 72 + oct * 8] = rv;
    }
#pragma unroll
    for (int i = 0; i < 4; ++i) {
        sq[i] += __shfl_xor(sq[i], 1);
        sq[i] += __shfl_xor(sq[i], 2);
        sq[i] += __shfl_xor(sq[i], 4);
        if ((t & 7) == 0)
            rsl_lds[(t >> 3) + i * 32] = 1.4426950408889634f / fmaxf(sqrtf(sq[i]), 1e-12f);
    }
    __syncthreads();

    const int wr = (w >> 1) * 64, wc = (w & 1) * 64;
    f32x4v acc[4][4];
#pragma unroll
    for (int i = 0; i < 4; ++i)
#pragma unroll
        for (int j = 0; j < 4; ++j)
#pragma unroll
            for (int e = 0; e < 4; ++e) acc[i][j][e] = 0.f;
#pragma unroll
    for (int ks = 0; ks < 2; ++ks) {
        s16x8 af[4], bfr[4];
#pragma unroll
        for (int fi = 0; fi < 4; ++fi)
            af[fi] = *(const s16x8*)&Xs[(wr + fi * 16 + l15) * 72 + ks * 32 + l4 * 8];
#pragma unroll
        for (int fj = 0; fj < 4; ++fj)
            bfr[fj] = *(const s16x8*)&RMs[(wc + fj * 16 + l15) * 72 + ks * 32 + l4 * 8];
#pragma unroll
        for (int fi = 0; fi < 4; ++fi)
#pragma unroll
            for (int fj = 0; fj < 4; ++fj)
                acc[fi][fj] = __builtin_amdgcn_mfma_f32_16x16x32_bf16(af[fi], bfr[fj], acc[fi][fj], 0, 0, 0);
    }

#pragma unroll
    for (int fi = 0; fi < 4; ++fi)
#pragma unroll
        for (int reg = 0; reg < 4; ++reg) {
            const int row = wr + fi * 16 + l4 * 4 + reg;
            const float rsl = rsl_lds[row];
            const size_t base = ((size_t)(r0 + row) * 16 + h) * 256;
#pragma unroll
            for (int fj = 0; fj < 4; ++fj) {
                const int d = wc + fj * 16 + l15;
                const float arg = acc[fi][fj][reg] * rsl;
                PHI[base + d]       = f2bf(exp2f_hw(arg - 4.f));
                PHI[base + 128 + d] = f2bf(exp2f_hw(-arg - 4.f));
            }
        }
}

// ---------------------------------------------------------------------------
// Chunk state via MFMA -> bf16 chunk sums (stc).
__global__ __launch_bounds__(256) void chunk_state_mfma(
    const u16* __restrict__ PHIK, const u16* __restrict__ VPT, u16* __restrict__ STC)
{
    __shared__ __align__(16) u16 Ks[64 * 136];
    __shared__ float zlds[16][132];
    const int b = blockIdx.x;
    const int c = blockIdx.y >> 1;
    const int dh = blockIdx.y & 1;
    const int t = threadIdx.x;
    const int wid = t >> 6, lane = t & 63;
    const int l15 = lane & 15, l4 = lane >> 4;
    const int wr = wid >> 1, wc = wid & 1;

    const size_t R0 = (size_t)b * 2048 + (size_t)c * 256;
    const int rgrp = t >> 4, d08 = (t & 15) * 8;

    float zpart[8];
#pragma unroll
    for (int i = 0; i < 8; ++i) zpart[i] = 0.f;

    f32x4v acc[2][4];
#pragma unroll
    for (int i = 0; i < 2; ++i)
#pragma unroll
        for (int j = 0; j < 4; ++j)
#pragma unroll
            for (int e = 0; e < 4; ++e) acc[i][j][e] = 0.f;

    for (int stage = 0; stage < 4; ++stage) {
        __syncthreads();
#pragma unroll
        for (int j = 0; j < 4; ++j) {
            const int r = rgrp + 16 * j;
            const uint4 v = *(const uint4*)(PHIK + (R0 + stage * 64 + r) * 256 + dh * 128 + d08);
            const int x = ((r >> 3) & 3) << 1;
            *(uint4*)&Ks[r * 136 + (((d08 >> 3) ^ x) << 3)] = v;
            const u16* pv = (const u16*)&v;
#pragma unroll
            for (int i = 0; i < 8; ++i) zpart[i] += bf2f(pv[i]);
        }
        __syncthreads();
#pragma unroll
        for (int ks = 0; ks < 2; ++ks) {
            const int xk = ((ks * 4 + l4) & 3) << 1;
            const int r0 = ks * 32 + l4 * 8;
            s16x8 af[2], bk[4];
#pragma unroll
            for (int fi = 0; fi < 2; ++fi) {
                const int h = wr * 32 + fi * 16 + l15;
                af[fi] = *(const s16x8*)(VPT + ((size_t)b * 64 + h) * 2048 + c * 256 + stage * 64 + ks * 32 + l4 * 8);
            }
#pragma unroll
            for (int fj = 0; fj < 4; ++fj) {
                const int d = wc * 64 + fj * 16 + l15;
                const int colk = (((d >> 3) ^ xk) << 3) + (d & 7);
#pragma unroll
                for (int e = 0; e < 8; ++e)
                    bk[fj][e] = (short)Ks[(r0 + e) * 136 + colk];
            }
#pragma unroll
            for (int fi = 0; fi < 2; ++fi)
#pragma unroll
                for (int fj = 0; fj < 4; ++fj)
                    acc[fi][fj] = __builtin_amdgcn_mfma_f32_16x16x32_bf16(af[fi], bk[fj], acc[fi][fj], 0, 0, 0);
        }
    }
    __syncthreads();
    *(float4*)&zlds[rgrp][d08]     = *(float4*)&zpart[0];
    *(float4*)&zlds[rgrp][d08 + 4] = *(float4*)&zpart[4];
    __syncthreads();
    u16* st = STC + (size_t)(b * 8 + c) * 16640;
    if (t < 128) {
        float z = 0.f;
#pragma unroll
        for (int g = 0; g < 16; ++g) z += zlds[g][t];
        st[16384 + dh * 128 + t] = f2bf(z);
    }
#pragma unroll
    for (int fi = 0; fi < 2; ++fi)
#pragma unroll
        for (int reg = 0; reg < 4; ++reg) {
            const int h = wr * 32 + fi * 16 + l4 * 4 + reg;
#pragma unroll
            for (int fj = 0; fj < 4; ++fj) {
                const int d = dh * 128 + wc * 64 + fj * 16 + l15;
                st[(size_t)h * 256 + d] = f2bf(acc[fi][fj][reg]);
            }
        }
}

// ---------------------------------------------------------------------------
// Exclusive prefix over 8 chunks (f32 accumulation of bf16 chunk sums).
__global__ void prefix_scan(const u16* __restrict__ STC, u16* __restrict__ STBF)
{
    const int b = blockIdx.x;
    const int e = blockIdx.y * 256 + threadIdx.x;
    if (e >= 16640) return;
    float run = 0.f;
#pragma unroll
    for (int c = 0; c < 8; ++c) {
        const size_t idx = (size_t)(b * 8 + c) * 16640 + e;
        const float v = bf2f(STC[idx]);
        STBF[idx] = f2bf(run);
        run += v;
    }
}

// ---------------------------------------------------------------------------
// Fused causal kernel — round-10 version (known-good, 78 us). 2-wave blocks;
// wave w handles rf = pair / 7-pair (balanced). XCD-grouped: bid%8 = b-group.
__global__ __launch_bounds__(128) void causal_fused(
    const u16* __restrict__ PHIQ, const u16* __restrict__ PHIK,
    const u16* __restrict__ VPT, const u16* __restrict__ STBF,
    u16* __restrict__ ATT)
{
    const u32 bid = blockIdx.x;
    const int pair = (int)((bid >> 3) & 3);
    const int G  = (int)((bid >> 5) * 8 + (bid & 7));   // = c*64 + b
    const int b  = G & 63;
    const int c  = G >> 6;
    const int w  = threadIdx.x >> 6;
    const int rf = w ? (7 - pair) : pair;
    const int ri = rf >> 1, fi = rf & 1;
    const int lane = threadIdx.x & 63;
    const int l31 = lane & 31, s = lane >> 5;
    const size_t chunk0 = (size_t)b * 2048 + (size_t)c * 256;
    const u16* stb = STBF + (size_t)(b * 8 + c) * 16640;

    const int qc = ri * 64 + fi * 32 + l31;
    s16x8 qf[16];
    const u16* qp = PHIQ + (chunk0 + qc) * 256 + s * 8;
#pragma unroll
    for (int ds = 0; ds < 16; ++ds)
        qf[ds] = *(const s16x8*)(qp + ds * 16);

    f32x16v o[2], o2;
#pragma unroll
    for (int e = 0; e < 16; ++e) { o[0][e] = 0.f; o[1][e] = 0.f; o2[e] = 0.f; }
    float den = 0.f;

    // ---- inter: o += Q.S^T ; o2 += Q.z (den per D-row)
#pragma unroll
    for (int ds = 0; ds < 16; ++ds) {
        const s16x8 zf = *(const s16x8*)(stb + 16384 + ds * 16 + s * 8);
        o2 = __builtin_amdgcn_mfma_f32_32x32x16_bf16(qf[ds], zf, o2, 0, 0, 0);
#pragma unroll
        for (int fh = 0; fh < 2; ++fh) {
            const s16x8 sx = *(const s16x8*)(stb + (fh * 32 + l31) * 256 + ds * 16 + s * 8);
            o[fh] = __builtin_amdgcn_mfma_f32_32x32x16_bf16(qf[ds], sx, o[fh], 0, 0, 0);
        }
    }

    // ---- intra: swapped QK^T over 32-row k-blocks
    const int kbmax = ri * 2 + fi;
    for (int kb = 0; kb <= kbmax; ++kb) {
        s16x8 vf[2][2];
#pragma unroll
        for (int kh = 0; kh < 2; ++kh)
#pragma unroll
            for (int fh = 0; fh < 2; ++fh)
                vf[kh][fh] = *(const s16x8*)(VPT + ((size_t)b * 64 + fh * 32 + l31) * 2048
                                             + c * 256 + kb * 32 + kh * 16 + s * 8);
        f32x16v p0, p1;
#pragma unroll
        for (int e = 0; e < 16; ++e) { p0[e] = 0.f; p1[e] = 0.f; }
        const u16* kptr = PHIK + (chunk0 + kb * 32 + l31) * 256 + s * 8;
#pragma unroll
        for (int ds = 0; ds < 8; ++ds) {
            const s16x8 kf0 = *(const s16x8*)(kptr + (2 * ds) * 16);
            const s16x8 kf1 = *(const s16x8*)(kptr + (2 * ds + 1) * 16);
            p0 = __builtin_amdgcn_mfma_f32_32x32x16_bf16(kf0, qf[2 * ds],     p0, 0, 0, 0);
            p1 = __builtin_amdgcn_mfma_f32_32x32x16_bf16(kf1, qf[2 * ds + 1], p1, 0, 0, 0);
        }
        f32x16v p;
#pragma unroll
        for (int e = 0; e < 16; ++e) p[e] = p0[e] + p1[e];

        const bool diag = (kb == kbmax);
        float rsum = 0.f;
#pragma unroll
        for (int reg = 0; reg < 16; ++reg) {
            if (diag) {
                const int kc = kb * 32 + (reg & 3) + 8 * (reg >> 2) + 4 * s;
                if (kc > qc) p[reg] = 0.f;
            }
            rsum += p[reg];
        }
        den += rsum;
#pragma unroll
        for (int kh = 0; kh < 2; ++kh) {
            const u32 pA_lo = cvtpk(p[8*kh + 0], p[8*kh + 1]);
            const u32 pA_hi = cvtpk(p[8*kh + 2], p[8*kh + 3]);
            const u32 pB_lo = cvtpk(p[8*kh + 4], p[8*kh + 5]);
            const u32 pB_hi = cvtpk(p[8*kh + 6], p[8*kh + 7]);
            const u32 X_lo = s ? pB_lo : pA_lo;
            const u32 X_hi = s ? pB_hi : pA_hi;
            const u32 Y_lo = s ? pA_lo : pB_lo;
            const u32 Y_hi = s ? pA_hi : pB_hi;
            const u32 sY_lo = __shfl_xor((int)Y_lo, 32);
            const u32 sY_hi = __shfl_xor((int)Y_hi, 32);
            u32 wq[4];
            wq[0] = s ? sY_lo : X_lo;
            wq[1] = s ? sY_hi : X_hi;
            wq[2] = s ? X_lo : sY_lo;
            wq[3] = s ? X_hi : sY_hi;
            s16x8 pa;
#pragma unroll
            for (int i = 0; i < 4; ++i) {
                pa[2*i]   = (short)(wq[i] & 0xffff);
                pa[2*i+1] = (short)(wq[i] >> 16);
            }
            o[0] = __builtin_amdgcn_mfma_f32_32x32x16_bf16(pa, vf[kh][0], o[0], 0, 0, 0);
            o[1] = __builtin_amdgcn_mfma_f32_32x32x16_bf16(pa, vf[kh][1], o[1], 0, 0, 0);
        }
    }

    // ---- epilogue
    const float denT = den + __shfl_xor(den, 32);
#pragma unroll
    for (int reg = 0; reg < 16; ++reg) {
        const int q32 = (reg & 3) + 8 * (reg >> 2) + 4 * s;
        const float dv = o2[reg] + __shfl(denT, q32);
        const float inv = 1.f / (dv + 1e-6f);
        const int qrow = c * 256 + ri * 64 + fi * 32 + q32;
        const size_t abase = (size_t)qrow * 4096 + b * 64;
        ATT[abase + l31]      = f2bf(o[0][reg] * inv);
        ATT[abase + 32 + l31] = f2bf(o[1][reg] * inv);
    }
}

// ---------------------------------------------------------------------------
extern "C" void kernel_launch(void* const* d_in, const int* in_sizes, int n_in,
                              void* d_out, int out_size, void* d_ws, size_t ws_size,
                              hipStream_t stream)
{
    const float* query = (const float*)d_in[0];
    const float* key   = (const float*)d_in[1];
    const float* value = (const float*)d_in[2];
    const float* wq    = (const float*)d_in[3];
    const float* bq    = (const float*)d_in[4];
    const float* wk    = (const float*)d_in[5];
    const float* bk    = (const float*)d_in[6];
    const float* wv    = (const float*)d_in[7];
    const float* bv    = (const float*)d_in[8];
    const float* wo    = (const float*)d_in[9];
    const float* bo    = (const float*)d_in[10];
    const float* rm    = (const float*)d_in[11];
    float* out = (float*)d_out;

    // Workspace (220,987,392 B <= proven 235,929,600 B). Overlays (ordered):
    //   wqkv lives in phiq head (dead before rand_project writes phiq)
    //   xq/xk overlay the stc/stbf region (dead after gemm_qkv; stc/stbf written later)
    //   attn overlays qp (dead after rand_project)
    char* base = (char*)d_ws;
    u16* phiq = (u16*)(base);                    //  67,108,864
    u16* phik = (u16*)(base +  67108864);        //  67,108,864
    u16* vpt  = (u16*)(base + 134217728);        //  16,777,216
    u16* qp   = (u16*)(base + 150994944);        //  16,777,216 (-> attn overlay)
    u16* kp   = (u16*)(base + 167772160);        //  16,777,216
    u16* stc  = (u16*)(base + 184549376);        //  17,039,360
    u16* stbf = (u16*)(base + 201588736);        //  17,039,360 (ends 218,628,096)
    u16* xq   = (u16*)(base + 184549376);        //  16,777,216 (overlay stc)
    u16* xk   = (u16*)(base + 201326592);        //  16,777,216 (overlay stc/stbf)
    u16* wob  = (u16*)(base + 218628096);        //   2,097,152
    u16* rmb  = (u16*)(base + 220725248);        //     262,144 (ends 220,987,392)
    u16* wqkv = phiq;                            //   6,291,456 (phiq head overlay)
    u16* attn = qp;

    const dim3 blk(256);
    cvt_consts<<<dim3(4096, 7), blk, 0, stream>>>(wq, wk, wv, wo, rm, query, key,
                                                  wqkv, wob, rmb, xq, xk);
    gemm_qkv<<<dim3(64, 8, 3), blk, 0, stream>>>(xq, xk, value, wqkv, bq, bk, bv, qp, kp, vpt);
    rand_project_mfma<<<dim3(16, 64, 2), blk, 0, stream>>>(qp, kp, rmb, phiq, phik);
    chunk_state_mfma<<<dim3(64, 16), blk, 0, stream>>>(phik, vpt, stc);
    prefix_scan<<<dim3(64, 65), blk, 0, stream>>>(stc, stbf);
    causal_fused<<<dim3(2048), dim3(128), 0, stream>>>(phiq, phik, vpt, stbf, attn);
    gemm_o<<<dim3(64, 8), blk, 0, stream>>>(attn, wob, bo, out);
}

// Round 14
// 279.095 us; speedup vs baseline: 1.3519x; 1.0235x over previous
//
#include <hip/hip_runtime.h>
#include <math.h>

// Dims: L=2048 N=4 E=1024 H=16 D=128 HD=64; 2D=256; M=L*N=8192; B=64
// phi natural (l,n,h,d) flat order == reference's scrambled (b,l',d) view.
// attn row mapping: flat l*4096 + b*64 + hd == (l*4+nb)*1024 + (h16*64+hd), b=nb*16+h16.
// Chunked causal: CHK=256, NC=8.
// GEMMs: BK=64 (halved barrier-drain count), LDS [128][64] with slot^(row&7)
// swizzle realized via pre-swizzled global source (rule #21); linear gload_lds dest.

typedef unsigned short u16;
typedef unsigned int u32;
using f32x4v  = __attribute__((ext_vector_type(4))) float;
using f32x16v = __attribute__((ext_vector_type(16))) float;
using s16x8   = __attribute__((ext_vector_type(8))) short;

__device__ __forceinline__ float bf2f(u16 u) { return __uint_as_float(((u32)u) << 16); }
__device__ __forceinline__ u16 f2bf(float x) {
    u32 b = __float_as_uint(x);
    b += 0x7fff + ((b >> 16) & 1);          // RNE
    return (u16)(b >> 16);
}
__device__ __forceinline__ u32 cvtpk(float lo, float hi) {
    u32 r;
    asm("v_cvt_pk_bf16_f32 %0, %1, %2" : "=v"(r) : "v"(lo), "v"(hi));
    return r;
}
__device__ __forceinline__ float exp2f_hw(float x) {
    float r;
    asm("v_exp_f32 %0, %1" : "=v"(r) : "v"(x));
    return r;
}
__device__ __forceinline__ void gload_lds16(const void* g, void* l) {
    __builtin_amdgcn_global_load_lds(
        (const __attribute__((address_space(1))) void*)g,
        (__attribute__((address_space(3))) void*)l, 16, 0, 0);
}

// ---------------------------------------------------------------------------
// All f32->bf16 conversions in one launch: y = 0..3 weights, 4 rm, 5 query, 6 key
__global__ __launch_bounds__(256) void cvt_consts(
    const float* __restrict__ w0, const float* __restrict__ w1,
    const float* __restrict__ w2, const float* __restrict__ w3,
    const float* __restrict__ rm, const float* __restrict__ query,
    const float* __restrict__ key, u16* __restrict__ wqkv,
    u16* __restrict__ wob, u16* __restrict__ rmb,
    u16* __restrict__ xq, u16* __restrict__ xk)
{
    const int y = blockIdx.y;
    const float* src;
    u16* d;
    int nblk;
    switch (y) {
        case 0: src = w0; d = wqkv;            nblk = 512;  break;
        case 1: src = w1; d = wqkv + 1048576;  nblk = 512;  break;
        case 2: src = w2; d = wqkv + 2097152;  nblk = 512;  break;
        case 3: src = w3; d = wob;             nblk = 512;  break;
        case 4: src = rm; d = rmb;             nblk = 64;   break;
        case 5: src = query; d = xq;           nblk = 4096; break;
        default: src = key; d = xk;            nblk = 4096; break;
    }
    if ((int)blockIdx.x >= nblk) return;
    const size_t i = ((size_t)blockIdx.x * 256 + threadIdx.x) * 8;
    const float4 a = *(const float4*)(src + i);
    const float4 b = *(const float4*)(src + i + 4);
    u16 o[8] = {f2bf(a.x), f2bf(a.y), f2bf(a.z), f2bf(a.w),
                f2bf(b.x), f2bf(b.y), f2bf(b.z), f2bf(b.w)};
    *(uint4*)(d + i) = *(uint4*)o;
}

// ---------------------------------------------------------------------------
// QKV projection GEMM, one dispatch (z selects). BK=64. z<2: A = bf16 via
// swizzled-source gload_lds. z==2: A = f32 value, reg-staged + converted into
// the same swizzle. B = bf16 weights via swizzled-source gload_lds.
// z<2 -> bf16 row-major (qp/kp); z==2 -> vpt[(b*64+hd)*2048 + k].
__global__ __launch_bounds__(256) void gemm_qkv(
    const u16* __restrict__ XQ, const u16* __restrict__ XK, const float* __restrict__ Xv,
    const u16* __restrict__ WB, const float* __restrict__ bq, const float* __restrict__ bk,
    const float* __restrict__ bv, u16* __restrict__ qp, u16* __restrict__ kp, u16* __restrict__ vpt)
{
    __shared__ __align__(16) u16 As[8192];   // [128][64], phys slot = ls ^ (row&7)
    __shared__ __align__(16) u16 Bs[8192];
    const int z = blockIdx.z;
    const u16* Bw = WB + (size_t)z * 1048576;
    const float* bias = (z == 0) ? bq : (z == 1) ? bk : bv;

    const int t = threadIdx.x;
    const int m0 = blockIdx.x * 128, n0 = blockIdx.y * 128;
    const int wid = t >> 6, lane = t & 63;
    const int wr = wid >> 1, wc = wid & 1;
    const int l15 = lane & 15, l4 = lane >> 4;

    f32x4v acc[4][4];
#pragma unroll
    for (int i = 0; i < 4; ++i)
#pragma unroll
        for (int j = 0; j < 4; ++j)
#pragma unroll
            for (int e = 0; e < 4; ++e) acc[i][j][e] = 0.f;

    // gload_lds staging: instr i (0..3) stages 8 rows: row = wid*32 + i*8 + (lane>>3),
    // phys slot = lane&7. row&7 == lane>>3 (instr-invariant) -> swizzled source col:
    const int grow = wid * 32 + (lane >> 3);
    const int lcol = ((lane & 7) ^ (lane >> 3)) * 8;
    const u16* gbB = Bw + (size_t)(n0 + grow) * 1024 + lcol;
    const u16* XA  = (z == 0) ? XQ : XK;
    const u16* gaA = XA + (size_t)(m0 + grow) * 1024 + lcol;
    // z==2 f32 path: thread t -> row t>>1, col-half (t&1)*32 (logical slots half*4+q)
    const int srow = t >> 1;
    const int half = t & 1;
    const float* gsrcA = Xv + (size_t)(m0 + srow) * 1024 + half * 32;

    for (int k0 = 0; k0 < 1024; k0 += 64) {
        __syncthreads();
#pragma unroll
        for (int i = 0; i < 4; ++i)
            gload_lds16(gbB + (size_t)i * 8 * 1024 + k0, &Bs[(wid * 32 + i * 8) * 64]);
        if (z < 2) {
#pragma unroll
            for (int i = 0; i < 4; ++i)
                gload_lds16(gaA + (size_t)i * 8 * 1024 + k0, &As[(wid * 32 + i * 8) * 64]);
        } else {
            u16 ta[32];
#pragma unroll
            for (int q = 0; q < 8; ++q) {
                const float4 v = *(const float4*)(gsrcA + k0 + q * 4);
                ta[q*4+0] = f2bf(v.x); ta[q*4+1] = f2bf(v.y);
                ta[q*4+2] = f2bf(v.z); ta[q*4+3] = f2bf(v.w);
            }
#pragma unroll
            for (int q = 0; q < 4; ++q) {
                const int phys = (half * 4 + q) ^ (srow & 7);
                *(uint4*)&As[srow * 64 + phys * 8] = *(const uint4*)&ta[q * 8];
            }
        }
        __syncthreads();
#pragma unroll
        for (int ks = 0; ks < 2; ++ks) {
            s16x8 af[4], bfr[4];
#pragma unroll
            for (int fi = 0; fi < 4; ++fi) {
                const int r = wr * 64 + fi * 16 + l15;
                const int phys = (ks * 4 + l4) ^ (r & 7);
                af[fi] = *(const s16x8*)&As[r * 64 + phys * 8];
            }
#pragma unroll
            for (int fj = 0; fj < 4; ++fj) {
                const int r = wc * 64 + fj * 16 + l15;
                const int phys = (ks * 4 + l4) ^ (r & 7);
                bfr[fj] = *(const s16x8*)&Bs[r * 64 + phys * 8];
            }
#pragma unroll
            for (int fi = 0; fi < 4; ++fi)
#pragma unroll
                for (int fj = 0; fj < 4; ++fj)
                    acc[fi][fj] = __builtin_amdgcn_mfma_f32_16x16x32_bf16(af[fi], bfr[fj], acc[fi][fj], 0, 0, 0);
        }
    }

    u16* Cp = (z == 0) ? qp : (z == 1) ? kp : vpt;
    const int rl = l4 * 4, cl = l15;
    float bvals[4];
#pragma unroll
    for (int fj = 0; fj < 4; ++fj) bvals[fj] = bias[n0 + wc * 64 + fj * 16 + cl];
#pragma unroll
    for (int fi = 0; fi < 4; ++fi)
#pragma unroll
        for (int j = 0; j < 4; ++j) {
            const size_t m = m0 + wr * 64 + fi * 16 + rl + j;
#pragma unroll
            for (int fj = 0; fj < 4; ++fj) {
                const int n = n0 + wc * 64 + fj * 16 + cl;
                const float v = acc[fi][fj][j] + bvals[fj];
                if (z < 2) Cp[m * 1024 + n] = f2bf(v);
                else       Cp[((size_t)((m & 3) * 16 + (n >> 6)) * 64 + (n & 63)) * 2048 + (m >> 2)] = f2bf(v);
            }
        }
}

// ---------------------------------------------------------------------------
// Output GEMM: BK=64, A bf16 + B bf16 via swizzled-source gload_lds, f32 out.
__global__ __launch_bounds__(256) void gemm_o(
    const u16* __restrict__ A, const u16* __restrict__ Bw,
    const float* __restrict__ bias, float* __restrict__ Cp)
{
    __shared__ __align__(16) u16 As[8192];
    __shared__ __align__(16) u16 Bs[8192];
    const int t = threadIdx.x;
    const int m0 = blockIdx.x * 128, n0 = blockIdx.y * 128;
    const int wid = t >> 6, lane = t & 63;
    const int wr = wid >> 1, wc = wid & 1;
    const int l15 = lane & 15, l4 = lane >> 4;

    f32x4v acc[4][4];
#pragma unroll
    for (int i = 0; i < 4; ++i)
#pragma unroll
        for (int j = 0; j < 4; ++j)
#pragma unroll
            for (int e = 0; e < 4; ++e) acc[i][j][e] = 0.f;

    const int grow = wid * 32 + (lane >> 3);
    const int lcol = ((lane & 7) ^ (lane >> 3)) * 8;
    const u16* gaA = A  + (size_t)(m0 + grow) * 1024 + lcol;
    const u16* gbB = Bw + (size_t)(n0 + grow) * 1024 + lcol;

    for (int k0 = 0; k0 < 1024; k0 += 64) {
        __syncthreads();
#pragma unroll
        for (int i = 0; i < 4; ++i) {
            gload_lds16(gaA + (size_t)i * 8 * 1024 + k0, &As[(wid * 32 + i * 8) * 64]);
            gload_lds16(gbB + (size_t)i * 8 * 1024 + k0, &Bs[(wid * 32 + i * 8) * 64]);
        }
        __syncthreads();
#pragma unroll
        for (int ks = 0; ks < 2; ++ks) {
            s16x8 af[4], bfr[4];
#pragma unroll
            for (int fi = 0; fi < 4; ++fi) {
                const int r = wr * 64 + fi * 16 + l15;
                const int phys = (ks * 4 + l4) ^ (r & 7);
                af[fi] = *(const s16x8*)&As[r * 64 + phys * 8];
            }
#pragma unroll
            for (int fj = 0; fj < 4; ++fj) {
                const int r = wc * 64 + fj * 16 + l15;
                const int phys = (ks * 4 + l4) ^ (r & 7);
                bfr[fj] = *(const s16x8*)&Bs[r * 64 + phys * 8];
            }
#pragma unroll
            for (int fi = 0; fi < 4; ++fi)
#pragma unroll
                for (int fj = 0; fj < 4; ++fj)
                    acc[fi][fj] = __builtin_amdgcn_mfma_f32_16x16x32_bf16(af[fi], bfr[fj], acc[fi][fj], 0, 0, 0);
        }
    }

    const int rl = l4 * 4, cl = l15;
    float bvals[4];
#pragma unroll
    for (int fj = 0; fj < 4; ++fj) bvals[fj] = bias[n0 + wc * 64 + fj * 16 + cl];
#pragma unroll
    for (int fi = 0; fi < 4; ++fi)
#pragma unroll
        for (int j = 0; j < 4; ++j) {
            const size_t m = m0 + wr * 64 + fi * 16 + rl + j;
#pragma unroll
            for (int fj = 0; fj < 4; ++fj) {
                const int n = n0 + wc * 64 + fj * 16 + cl;
                Cp[m * 1024 + n] = acc[fi][fj][j] + bvals[fj];
            }
        }
}

// ---------------------------------------------------------------------------
// Random projection via MFMA (round-10 verified).
__global__ __launch_bounds__(256) void rand_project_mfma(
    const u16* __restrict__ QP, const u16* __restrict__ KP,
    const u16* __restrict__ RMB, u16* __restrict__ PHIQ, u16* __restrict__ PHIK)
{
    const u16* X  = (blockIdx.z == 0) ? QP : KP;
    u16* PHI      = (blockIdx.z == 0) ? PHIQ : PHIK;
    __shared__ __align__(16) u16 Xs[128 * 72];
    __shared__ __align__(16) u16 RMs[128 * 72];
    __shared__ float rsl_lds[128];
    const int h  = blockIdx.x;
    const int r0 = blockIdx.y * 128;
    const int t  = threadIdx.x;
    const int w  = t >> 6, lane = t & 63;
    const int l15 = lane & 15, l4 = lane >> 4;

    float sq[4];
#pragma unroll
    for (int i = 0; i < 4; ++i) {
        const int lin = t + i * 256;
        const int row = lin >> 3, oct = lin & 7;
        const uint4 xv = *(const uint4*)(X + (size_t)(r0 + row) * 1024 + h * 64 + oct * 8);
        *(uint4*)&Xs[row * 72 + oct * 8] = xv;
        const u16* pv = (const u16*)&xv;
        float s = 0.f;
#pragma unroll
        for (int e = 0; e < 8; ++e) { const float f = bf2f(pv[e]); s += f * f; }
        sq[i] = s;
        const uint4 rv = *(const uint4*)(RMB + (size_t)h * 8192 + lin * 8);
        *(uint4*)&RMs[row * 72 + oct * 8] = rv;
    }
#pragma unroll
    for (int i = 0; i < 4; ++i) {
        sq[i] += __shfl_xor(sq[i], 1);
        sq[i] += __shfl_xor(sq[i], 2);
        sq[i] += __shfl_xor(sq[i], 4);
        if ((t & 7) == 0)
            rsl_lds[(t >> 3) + i * 32] = 1.4426950408889634f / fmaxf(sqrtf(sq[i]), 1e-12f);
    }
    __syncthreads();

    const int wr = (w >> 1) * 64, wc = (w & 1) * 64;
    f32x4v acc[4][4];
#pragma unroll
    for (int i = 0; i < 4; ++i)
#pragma unroll
        for (int j = 0; j < 4; ++j)
#pragma unroll
            for (int e = 0; e < 4; ++e) acc[i][j][e] = 0.f;
#pragma unroll
    for (int ks = 0; ks < 2; ++ks) {
        s16x8 af[4], bfr[4];
#pragma unroll
        for (int fi = 0; fi < 4; ++fi)
            af[fi] = *(const s16x8*)&Xs[(wr + fi * 16 + l15) * 72 + ks * 32 + l4 * 8];
#pragma unroll
        for (int fj = 0; fj < 4; ++fj)
            bfr[fj] = *(const s16x8*)&RMs[(wc + fj * 16 + l15) * 72 + ks * 32 + l4 * 8];
#pragma unroll
        for (int fi = 0; fi < 4; ++fi)
#pragma unroll
            for (int fj = 0; fj < 4; ++fj)
                acc[fi][fj] = __builtin_amdgcn_mfma_f32_16x16x32_bf16(af[fi], bfr[fj], acc[fi][fj], 0, 0, 0);
    }

#pragma unroll
    for (int fi = 0; fi < 4; ++fi)
#pragma unroll
        for (int reg = 0; reg < 4; ++reg) {
            const int row = wr + fi * 16 + l4 * 4 + reg;
            const float rsl = rsl_lds[row];
            const size_t base = ((size_t)(r0 + row) * 16 + h) * 256;
#pragma unroll
            for (int fj = 0; fj < 4; ++fj) {
                const int d = wc + fj * 16 + l15;
                const float arg = acc[fi][fj][reg] * rsl;
                PHI[base + d]       = f2bf(exp2f_hw(arg - 4.f));
                PHI[base + 128 + d] = f2bf(exp2f_hw(-arg - 4.f));
            }
        }
}

// ---------------------------------------------------------------------------
// Chunk state via MFMA -> bf16 chunk sums (stc).
__global__ __launch_bounds__(256) void chunk_state_mfma(
    const u16* __restrict__ PHIK, const u16* __restrict__ VPT, u16* __restrict__ STC)
{
    __shared__ __align__(16) u16 Ks[64 * 136];
    __shared__ float zlds[16][132];
    const int b = blockIdx.x;
    const int c = blockIdx.y >> 1;
    const int dh = blockIdx.y & 1;
    const int t = threadIdx.x;
    const int wid = t >> 6, lane = t & 63;
    const int l15 = lane & 15, l4 = lane >> 4;
    const int wr = wid >> 1, wc = wid & 1;

    const size_t R0 = (size_t)b * 2048 + (size_t)c * 256;
    const int rgrp = t >> 4, d08 = (t & 15) * 8;

    float zpart[8];
#pragma unroll
    for (int i = 0; i < 8; ++i) zpart[i] = 0.f;

    f32x4v acc[2][4];
#pragma unroll
    for (int i = 0; i < 2; ++i)
#pragma unroll
        for (int j = 0; j < 4; ++j)
#pragma unroll
            for (int e = 0; e < 4; ++e) acc[i][j][e] = 0.f;

    for (int stage = 0; stage < 4; ++stage) {
        __syncthreads();
#pragma unroll
        for (int j = 0; j < 4; ++j) {
            const int r = rgrp + 16 * j;
            const uint4 v = *(const uint4*)(PHIK + (R0 + stage * 64 + r) * 256 + dh * 128 + d08);
            const int x = ((r >> 3) & 3) << 1;
            *(uint4*)&Ks[r * 136 + (((d08 >> 3) ^ x) << 3)] = v;
            const u16* pv = (const u16*)&v;
#pragma unroll
            for (int i = 0; i < 8; ++i) zpart[i] += bf2f(pv[i]);
        }
        __syncthreads();
#pragma unroll
        for (int ks = 0; ks < 2; ++ks) {
            const int xk = ((ks * 4 + l4) & 3) << 1;
            const int r0 = ks * 32 + l4 * 8;
            s16x8 af[2], bk[4];
#pragma unroll
            for (int fi = 0; fi < 2; ++fi) {
                const int h = wr * 32 + fi * 16 + l15;
                af[fi] = *(const s16x8*)(VPT + ((size_t)b * 64 + h) * 2048 + c * 256 + stage * 64 + ks * 32 + l4 * 8);
            }
#pragma unroll
            for (int fj = 0; fj < 4; ++fj) {
                const int d = wc * 64 + fj * 16 + l15;
                const int colk = (((d >> 3) ^ xk) << 3) + (d & 7);
#pragma unroll
                for (int e = 0; e < 8; ++e)
                    bk[fj][e] = (short)Ks[(r0 + e) * 136 + colk];
            }
#pragma unroll
            for (int fi = 0; fi < 2; ++fi)
#pragma unroll
                for (int fj = 0; fj < 4; ++fj)
                    acc[fi][fj] = __builtin_amdgcn_mfma_f32_16x16x32_bf16(af[fi], bk[fj], acc[fi][fj], 0, 0, 0);
        }
    }
    __syncthreads();
    *(float4*)&zlds[rgrp][d08]     = *(float4*)&zpart[0];
    *(float4*)&zlds[rgrp][d08 + 4] = *(float4*)&zpart[4];
    __syncthreads();
    u16* st = STC + (size_t)(b * 8 + c) * 16640;
    if (t < 128) {
        float z = 0.f;
#pragma unroll
        for (int g = 0; g < 16; ++g) z += zlds[g][t];
        st[16384 + dh * 128 + t] = f2bf(z);
    }
#pragma unroll
    for (int fi = 0; fi < 2; ++fi)
#pragma unroll
        for (int reg = 0; reg < 4; ++reg) {
            const int h = wr * 32 + fi * 16 + l4 * 4 + reg;
#pragma unroll
            for (int fj = 0; fj < 4; ++fj) {
                const int d = dh * 128 + wc * 64 + fj * 16 + l15;
                st[(size_t)h * 256 + d] = f2bf(acc[fi][fj][reg]);
            }
        }
}

// ---------------------------------------------------------------------------
// Exclusive prefix over 8 chunks (f32 accumulation of bf16 chunk sums).
__global__ void prefix_scan(const u16* __restrict__ STC, u16* __restrict__ STBF)
{
    const int b = blockIdx.x;
    const int e = blockIdx.y * 256 + threadIdx.x;
    if (e >= 16640) return;
    float run = 0.f;
#pragma unroll
    for (int c = 0; c < 8; ++c) {
        const size_t idx = (size_t)(b * 8 + c) * 16640 + e;
        const float v = bf2f(STC[idx]);
        STBF[idx] = f2bf(run);
        run += v;
    }
}

// ---------------------------------------------------------------------------
// Fused causal kernel — round-10 version (known-good, 78 us). 2-wave blocks;
// wave w handles rf = pair / 7-pair (balanced). XCD-grouped: bid%8 = b-group.
__global__ __launch_bounds__(128) void causal_fused(
    const u16* __restrict__ PHIQ, const u16* __restrict__ PHIK,
    const u16* __restrict__ VPT, const u16* __restrict__ STBF,
    u16* __restrict__ ATT)
{
    const u32 bid = blockIdx.x;
    const int pair = (int)((bid >> 3) & 3);
    const int G  = (int)((bid >> 5) * 8 + (bid & 7));   // = c*64 + b
    const int b  = G & 63;
    const int c  = G >> 6;
    const int w  = threadIdx.x >> 6;
    const int rf = w ? (7 - pair) : pair;
    const int ri = rf >> 1, fi = rf & 1;
    const int lane = threadIdx.x & 63;
    const int l31 = lane & 31, s = lane >> 5;
    const size_t chunk0 = (size_t)b * 2048 + (size_t)c * 256;
    const u16* stb = STBF + (size_t)(b * 8 + c) * 16640;

    const int qc = ri * 64 + fi * 32 + l31;
    s16x8 qf[16];
    const u16* qp = PHIQ + (chunk0 + qc) * 256 + s * 8;
#pragma unroll
    for (int ds = 0; ds < 16; ++ds)
        qf[ds] = *(const s16x8*)(qp + ds * 16);

    f32x16v o[2], o2;
#pragma unroll
    for (int e = 0; e < 16; ++e) { o[0][e] = 0.f; o[1][e] = 0.f; o2[e] = 0.f; }
    float den = 0.f;

    // ---- inter: o += Q.S^T ; o2 += Q.z (den per D-row)
#pragma unroll
    for (int ds = 0; ds < 16; ++ds) {
        const s16x8 zf = *(const s16x8*)(stb + 16384 + ds * 16 + s * 8);
        o2 = __builtin_amdgcn_mfma_f32_32x32x16_bf16(qf[ds], zf, o2, 0, 0, 0);
#pragma unroll
        for (int fh = 0; fh < 2; ++fh) {
            const s16x8 sx = *(const s16x8*)(stb + (fh * 32 + l31) * 256 + ds * 16 + s * 8);
            o[fh] = __builtin_amdgcn_mfma_f32_32x32x16_bf16(qf[ds], sx, o[fh], 0, 0, 0);
        }
    }

    // ---- intra: swapped QK^T over 32-row k-blocks
    const int kbmax = ri * 2 + fi;
    for (int kb = 0; kb <= kbmax; ++kb) {
        s16x8 vf[2][2];
#pragma unroll
        for (int kh = 0; kh < 2; ++kh)
#pragma unroll
            for (int fh = 0; fh < 2; ++fh)
                vf[kh][fh] = *(const s16x8*)(VPT + ((size_t)b * 64 + fh * 32 + l31) * 2048
                                             + c * 256 + kb * 32 + kh * 16 + s * 8);
        f32x16v p0, p1;
#pragma unroll
        for (int e = 0; e < 16; ++e) { p0[e] = 0.f; p1[e] = 0.f; }
        const u16* kptr = PHIK + (chunk0 + kb * 32 + l31) * 256 + s * 8;
#pragma unroll
        for (int ds = 0; ds < 8; ++ds) {
            const s16x8 kf0 = *(const s16x8*)(kptr + (2 * ds) * 16);
            const s16x8 kf1 = *(const s16x8*)(kptr + (2 * ds + 1) * 16);
            p0 = __builtin_amdgcn_mfma_f32_32x32x16_bf16(kf0, qf[2 * ds],     p0, 0, 0, 0);
            p1 = __builtin_amdgcn_mfma_f32_32x32x16_bf16(kf1, qf[2 * ds + 1], p1, 0, 0, 0);
        }
        f32x16v p;
#pragma unroll
        for (int e = 0; e < 16; ++e) p[e] = p0[e] + p1[e];

        const bool diag = (kb == kbmax);
        float rsum = 0.f;
#pragma unroll
        for (int reg = 0; reg < 16; ++reg) {
            if (diag) {
                const int kc = kb * 32 + (reg & 3) + 8 * (reg >> 2) + 4 * s;
                if (kc > qc) p[reg] = 0.f;
            }
            rsum += p[reg];
        }
        den += rsum;
#pragma unroll
        for (int kh = 0; kh < 2; ++kh) {
            const u32 pA_lo = cvtpk(p[8*kh + 0], p[8*kh + 1]);
            const u32 pA_hi = cvtpk(p[8*kh + 2], p[8*kh + 3]);
            const u32 pB_lo = cvtpk(p[8*kh + 4], p[8*kh + 5]);
            const u32 pB_hi = cvtpk(p[8*kh + 6], p[8*kh + 7]);
            const u32 X_lo = s ? pB_lo : pA_lo;
            const u32 X_hi = s ? pB_hi : pA_hi;
            const u32 Y_lo = s ? pA_lo : pB_lo;
            const u32 Y_hi = s ? pA_hi : pB_hi;
            const u32 sY_lo = __shfl_xor((int)Y_lo, 32);
            const u32 sY_hi = __shfl_xor((int)Y_hi, 32);
            u32 wq[4];
            wq[0] = s ? sY_lo : X_lo;
            wq[1] = s ? sY_hi : X_hi;
            wq[2] = s ? X_lo : sY_lo;
            wq[3] = s ? X_hi : sY_hi;
            s16x8 pa;
#pragma unroll
            for (int i = 0; i < 4; ++i) {
                pa[2*i]   = (short)(wq[i] & 0xffff);
                pa[2*i+1] = (short)(wq[i] >> 16);
            }
            o[0] = __builtin_amdgcn_mfma_f32_32x32x16_bf16(pa, vf[kh][0], o[0], 0, 0, 0);
            o[1] = __builtin_amdgcn_mfma_f32_32x32x16_bf16(pa, vf[kh][1], o[1], 0, 0, 0);
        }
    }

    // ---- epilogue
    const float denT = den + __shfl_xor(den, 32);
#pragma unroll
    for (int reg = 0; reg < 16; ++reg) {
        const int q32 = (reg & 3) + 8 * (reg >> 2) + 4 * s;
        const float dv = o2[reg] + __shfl(denT, q32);
        const float inv = 1.f / (dv + 1e-6f);
        const int qrow = c * 256 + ri * 64 + fi * 32 + q32;
        const size_t abase = (size_t)qrow * 4096 + b * 64;
        ATT[abase + l31]      = f2bf(o[0][reg] * inv);
        ATT[abase + 32 + l31] = f2bf(o[1][reg] * inv);
    }
}

// ---------------------------------------------------------------------------
extern "C" void kernel_launch(void* const* d_in, const int* in_sizes, int n_in,
                              void* d_out, int out_size, void* d_ws, size_t ws_size,
                              hipStream_t stream)
{
    const float* query = (const float*)d_in[0];
    const float* key   = (const float*)d_in[1];
    const float* value = (const float*)d_in[2];
    const float* wq    = (const float*)d_in[3];
    const float* bq    = (const float*)d_in[4];
    const float* wk    = (const float*)d_in[5];
    const float* bk    = (const float*)d_in[6];
    const float* wv    = (const float*)d_in[7];
    const float* bv    = (const float*)d_in[8];
    const float* wo    = (const float*)d_in[9];
    const float* bo    = (const float*)d_in[10];
    const float* rm    = (const float*)d_in[11];
    float* out = (float*)d_out;

    // Workspace (220,987,392 B <= proven 235,929,600 B). Overlays (ordered):
    //   wqkv lives in phiq head (dead before rand_project writes phiq)
    //   xq/xk overlay the stc/stbf region (dead after gemm_qkv; stc/stbf written later)
    //   attn overlays qp (dead after rand_project)
    char* base = (char*)d_ws;
    u16* phiq = (u16*)(base);                    //  67,108,864
    u16* phik = (u16*)(base +  67108864);        //  67,108,864
    u16* vpt  = (u16*)(base + 134217728);        //  16,777,216
    u16* qp   = (u16*)(base + 150994944);        //  16,777,216 (-> attn overlay)
    u16* kp   = (u16*)(base + 167772160);        //  16,777,216
    u16* stc  = (u16*)(base + 184549376);        //  17,039,360
    u16* stbf = (u16*)(base + 201588736);        //  17,039,360 (ends 218,628,096)
    u16* xq   = (u16*)(base + 184549376);        //  16,777,216 (overlay stc)
    u16* xk   = (u16*)(base + 201326592);        //  16,777,216 (overlay stc/stbf)
    u16* wob  = (u16*)(base + 218628096);        //   2,097,152
    u16* rmb  = (u16*)(base + 220725248);        //     262,144 (ends 220,987,392)
    u16* wqkv = phiq;                            //   6,291,456 (phiq head overlay)
    u16* attn = qp;

    const dim3 blk(256);
    cvt_consts<<<dim3(4096, 7), blk, 0, stream>>>(wq, wk, wv, wo, rm, query, key,
                                                  wqkv, wob, rmb, xq, xk);
    gemm_qkv<<<dim3(64, 8, 3), blk, 0, stream>>>(xq, xk, value, wqkv, bq, bk, bv, qp, kp, vpt);
    rand_project_mfma<<<dim3(16, 64, 2), blk, 0, stream>>>(qp, kp, rmb, phiq, phik);
    chunk_state_mfma<<<dim3(64, 16), blk, 0, stream>>>(phik, vpt, stc);
    prefix_scan<<<dim3(64, 65), blk, 0, stream>>>(stc, stbf);
    causal_fused<<<dim3(2048), dim3(128), 0, stream>>>(phiq, phik, vpt, stbf, attn);
    gemm_o<<<dim3(64, 8), blk, 0, stream>>>(attn, wob, bo, out);
}